// Round 14
// baseline (341.494 us; speedup 1.0000x reference)
//
#include <hip/hip_runtime.h>
#include <hip/hip_bf16.h>
#include <math.h>

#define N_NODES 100000
#define N_EDGES 1000000
#define N_GRAPHS 100
#define IN_F 128
#define HID 64
#define N_CLS 40
#define EPS 1e-5f
#define SB 512          // stats partial blocks (layer0)
#define SCAN_BLK 391    // 391*256 = 100096 >= N_NODES+1
#define NTILE 1563      // ceil(N_NODES/64); also gemm grids + gemm1 stats partial count

// histogram geometry
#define HRANGE 32768            // nodes per range (2 per u32 word)
#define HNR 4                   // ranges: 4*32768 >= N_NODES
#define HNC 32                  // edge chunks
#define HWORDS (HRANGE / 2)     // 16384 u32 words = 64KB LDS
#define HESLICE (N_EDGES / HNC) // 31250

// fill geometry (sub-ranges of 4096 nodes; 24KB LDS)
#define FRANGE 4096
#define FNR 25                  // 25*4096 = 102400 >= N_NODES

typedef __attribute__((ext_vector_type(8))) short bf16x8;
typedef __attribute__((ext_vector_type(4))) float f32x4;

__device__ __forceinline__ float gelu_exact(float x) {
    return 0.5f * x * (1.0f + erff(x * 0.70710678118654752f));
}

__device__ __forceinline__ unsigned short f2b(float f) {  // f32 -> bf16 RNE
    unsigned u = __builtin_bit_cast(unsigned, f);
    return (unsigned short)((u + 0x7FFFu + ((u >> 16) & 1u)) >> 16);
}
__device__ __forceinline__ float b2f(unsigned short h) {
    unsigned u = ((unsigned)h) << 16;
    return __builtin_bit_cast(float, u);
}

// ---------------- weight prep: Wt0[n][k] bf16 (n<64:W0, else Wr0), Wt1 likewise
__global__ void k_prep_w(const float* __restrict__ W0, const float* __restrict__ Wr0,
                         const float* __restrict__ W1, const float* __restrict__ Wr1,
                         unsigned short* __restrict__ Wt0, unsigned short* __restrict__ Wt1) {
    int t = blockIdx.x * 256 + threadIdx.x;
    for (int idx = t; idx < 128 * 128; idx += gridDim.x * 256) {
        int n = idx >> 7, k = idx & 127;
        float v = (n < 64) ? W0[k * 64 + n] : Wr0[k * 64 + (n - 64)];
        Wt0[n * 128 + k] = f2b(v);
    }
    for (int idx = t; idx < 128 * 64; idx += gridDim.x * 256) {
        int n = idx >> 6, k = idx & 63;
        float v = (n < 64) ? W1[k * 64 + n] : Wr1[k * 64 + (n - 64)];
        Wt1[n * 64 + k] = f2b(v);
    }
}

// ---------------- LDS-privatized degree histogram (no global atomics) ----------------
__global__ __launch_bounds__(256) void k_hist(const int* __restrict__ src,
                                              const int* __restrict__ dst,
                                              unsigned* __restrict__ P) {
    __shared__ unsigned h[HWORDS];
    int t = threadIdx.x;
    int b = blockIdx.x;
    int chunk = b & (HNC - 1);
    int job = b >> 5;
    int range = job & (HNR - 1);
    const int* v = (job < HNR) ? dst : src;
    int base = range * HRANGE;
    for (int i = t; i < HWORDS; i += 256) h[i] = 0;
    __syncthreads();
    int e0 = chunk * HESLICE;
    for (int i = t; i < HESLICE / 2; i += 256) {
        uint2 d2 = *(const uint2*)(v + e0 + 2 * i);
        int o = (int)d2.x - base;
        if ((unsigned)o < HRANGE) atomicAdd(&h[o >> 1], 1u << ((o & 1) * 16));
        o = (int)d2.y - base;
        if ((unsigned)o < HRANGE) atomicAdd(&h[o >> 1], 1u << ((o & 1) * 16));
    }
    __syncthreads();
    unsigned* outp = P + (size_t)b * HWORDS;
    for (int i = t; i < HWORDS; i += 256) outp[i] = h[i];
}

// sum partials -> cnt_in, dn_in, dn_out; ALSO rewrite dst-partials in place as
// exclusive chunk-prefix (packed u16 add is carry-safe: per-node totals << 65536).
__global__ __launch_bounds__(256) void k_hist_reduce(unsigned* __restrict__ P,
                                                     int* __restrict__ cnt_in,
                                                     float* __restrict__ dn_in,
                                                     float* __restrict__ dn_out) {
    int w = blockIdx.x * 256 + threadIdx.x;   // 0 .. HNR*HWORDS-1 (65536)
    int range = w >> 14;
    int widx = w & (HWORDS - 1);
    unsigned* pin  = P + (size_t)(range * HNC) * HWORDS + widx;
    const unsigned* pout = P + (size_t)((HNR + range) * HNC) * HWORDS + widx;
    unsigned s_in = 0, s_out = 0;
    for (int c = 0; c < HNC; ++c) {
        unsigned v = pin[(size_t)c * HWORDS];
        pin[(size_t)c * HWORDS] = s_in;      // exclusive prefix along chunk axis
        s_in += v;
        s_out += pout[(size_t)c * HWORDS];
    }
    int n0 = range * HRANGE + widx * 2;
    unsigned ci0 = s_in & 0xFFFFu,  ci1 = s_in >> 16;
    unsigned co0 = s_out & 0xFFFFu, co1 = s_out >> 16;
    if (n0 < N_NODES) {
        cnt_in[n0] = (int)ci0;
        dn_in[n0]  = rsqrtf((float)(ci0 > 0 ? ci0 : 1));
        dn_out[n0] = rsqrtf((float)(co0 > 0 ? co0 : 1));
    }
    if (n0 + 1 < N_NODES) {
        cnt_in[n0 + 1] = (int)ci1;
        dn_in[n0 + 1]  = rsqrtf((float)(ci1 > 0 ? ci1 : 1));
        dn_out[n0 + 1] = rsqrtf((float)(co1 > 0 ? co1 : 1));
    }
}

// ---------------- CSR build ----------------
__global__ __launch_bounds__(256) void k_scan_reduce(const int* __restrict__ cnt,
                                                     int* __restrict__ bsum) {
    __shared__ int sh[256];
    int t = threadIdx.x;
    int i = blockIdx.x * 256 + t;
    int c = (i < N_NODES) ? cnt[i] : 0;
    sh[t] = c;
    __syncthreads();
    for (int d = 128; d > 0; d >>= 1) {
        if (t < d) sh[t] += sh[t + d];
        __syncthreads();
    }
    if (t == 0) bsum[blockIdx.x] = sh[0];
}

__global__ __launch_bounds__(512) void k_scan_bsum(const int* __restrict__ bsum,
                                                   int* __restrict__ bpre) {
    __shared__ int sh[512];
    int t = threadIdx.x;
    int v = (t < SCAN_BLK) ? bsum[t] : 0;
    sh[t] = v;
    __syncthreads();
    for (int d = 1; d < 512; d <<= 1) {
        int x = (t >= d) ? sh[t - d] : 0;
        __syncthreads();
        sh[t] += x;
        __syncthreads();
    }
    if (t < SCAN_BLK) bpre[t] = sh[t] - v;
}

__global__ __launch_bounds__(256) void k_scan_write(const int* __restrict__ cnt_in,
                                                    const int* __restrict__ bpre,
                                                    int* __restrict__ row_start) {
    __shared__ int sh[256];
    int t = threadIdx.x;
    int i = blockIdx.x * 256 + t;
    int c = (i < N_NODES) ? cnt_in[i] : 0;
    sh[t] = c;
    __syncthreads();
    for (int d = 1; d < 256; d <<= 1) {
        int v = (t >= d) ? sh[t - d] : 0;
        __syncthreads();
        sh[t] += v;
        __syncthreads();
    }
    int excl = sh[t] - c + bpre[blockIdx.x];
    if (i <= N_NODES) row_start[i] = excl;
}

// ---------------- atomic-free CSR fill (uint2 edge loads, unconditional) ----------------
__global__ __launch_bounds__(256) void k_fill2(const int* __restrict__ src,
                                               const int* __restrict__ dst,
                                               const int* __restrict__ row_start,
                                               const unsigned* __restrict__ Ppre,
                                               int* __restrict__ csr_src) {
    __shared__ unsigned base[FRANGE];       // 16 KB
    __shared__ unsigned curs[FRANGE / 2];   // 8 KB (packed u16 pairs)
    int t = threadIdx.x;
    int b = blockIdx.x;
    int c = b & (HNC - 1);
    int fr = b >> 5;
    int r = fr >> 3;                        // hist range (32768 nodes)
    int sub = fr & 7;                       // eighth within hist range
    int n0 = fr * FRANGE;
    const unsigned* pp = Ppre + (size_t)(r * HNC + c) * HWORDS + sub * (FRANGE / 2);
    for (int i = t; i < FRANGE / 2; i += 256) {
        unsigned pref = pp[i];
        int n = n0 + 2 * i;
        int2 rs = *(const int2*)(row_start + n);  // overread past N_NODES stays in ws; guarded
        base[2 * i]     = (n < N_NODES)     ? (unsigned)rs.x + (pref & 0xFFFFu) : 0u;
        base[2 * i + 1] = (n + 1 < N_NODES) ? (unsigned)rs.y + (pref >> 16)     : 0u;
        curs[i] = 0;
    }
    __syncthreads();
    int e0 = c * HESLICE;
    for (int i = t; i < HESLICE / 2; i += 256) {
        uint2 d2 = *(const uint2*)(dst + e0 + 2 * i);
        uint2 s2 = *(const uint2*)(src + e0 + 2 * i);
        int o0 = (int)d2.x - n0;
        if ((unsigned)o0 < FRANGE) {
            unsigned old = atomicAdd(&curs[o0 >> 1], 1u << ((o0 & 1) * 16));
            unsigned loc = (old >> ((o0 & 1) * 16)) & 0xFFFFu;
            csr_src[base[o0] + loc] = (int)s2.x;
        }
        int o1 = (int)d2.y - n0;
        if ((unsigned)o1 < FRANGE) {
            unsigned old = atomicAdd(&curs[o1 >> 1], 1u << ((o1 & 1) * 16));
            unsigned loc = (old >> ((o1 & 1) * 16)) & 0xFFFFu;
            csr_src[base[o1] + loc] = (int)s2.y;
        }
    }
}

// ---------------- layer0 MFMA GEMM (column-split waves, grid = NTILE) ----------------
// h0b = bf16(dn_out*(x@W0)), res0 = gelu(x@Wr0+br0)
// wave w owns cols w*32..w*32+31 (2 col-tiles), all 64 rows. bfrag = 32 VGPRs.
__global__ __launch_bounds__(256) void k_gemm0(
    const float* __restrict__ x, const unsigned short* __restrict__ Wt0,
    const float* __restrict__ br0, const float* __restrict__ dn_out,
    unsigned short* __restrict__ h0b, float* __restrict__ res0)
{
    __shared__ unsigned short xs[64][136];   // padded stride 272B
    int t = threadIdx.x;
    int lane = t & 63;
    int w = t >> 6;
    int g = lane >> 4, r16 = lane & 15;
    int rr = t >> 2, q4 = t & 3;

    bf16x8 bfrag[2][4];
    for (int i = 0; i < 2; ++i) {
        int n = (2 * w + i) * 16 + r16;
        for (int ks = 0; ks < 4; ++ks)
            bfrag[i][ks] = *(const bf16x8*)(Wt0 + n * 128 + ks * 32 + g * 8);
    }
    float br_c[2];
    for (int i = 0; i < 2; ++i) {
        int c = (2 * w + i) * 16 + r16;
        br_c[i] = (c >= 64) ? br0[c - 64] : 0.f;
    }

    for (int tile = blockIdx.x; tile < NTILE; tile += gridDim.x) {
        int row0 = tile * 64;
        {
            int R = row0 + rr;
            bool ok = (R < N_NODES);
            const float* xp = x + (size_t)R * IN_F + q4 * 32;
            for (int i = 0; i < 8; ++i) {
                float4 v = ok ? *(const float4*)(xp + i * 4) : make_float4(0.f, 0.f, 0.f, 0.f);
                unsigned p0 = (unsigned)f2b(v.x) | ((unsigned)f2b(v.y) << 16);
                unsigned p1 = (unsigned)f2b(v.z) | ((unsigned)f2b(v.w) << 16);
                *(uint2*)(&xs[rr][q4 * 32 + i * 4]) = make_uint2(p0, p1);
            }
        }
        __syncthreads();

        f32x4 acc[4][2];
        for (int rg16 = 0; rg16 < 4; ++rg16)
            for (int i = 0; i < 2; ++i)
                acc[rg16][i] = (f32x4){0.f, 0.f, 0.f, 0.f};

        for (int rg16 = 0; rg16 < 4; ++rg16) {
            int arow = rg16 * 16 + r16;
            bf16x8 a[4];
            for (int ks = 0; ks < 4; ++ks)
                a[ks] = *(const bf16x8*)(&xs[arow][ks * 32 + g * 8]);
            for (int ks = 0; ks < 4; ++ks)
                for (int i = 0; i < 2; ++i)
                    acc[rg16][i] = __builtin_amdgcn_mfma_f32_16x16x32_bf16(a[ks], bfrag[i][ks], acc[rg16][i], 0, 0, 0);
        }

        for (int rg16 = 0; rg16 < 4; ++rg16) {
            int Rbase = row0 + rg16 * 16 + g * 4;
            float dn[4];
            for (int rg = 0; rg < 4; ++rg) {
                int R = Rbase + rg;
                dn[rg] = (R < N_NODES) ? dn_out[R] : 0.f;
            }
            for (int i = 0; i < 2; ++i) {
                int c = (2 * w + i) * 16 + r16;
                for (int rg = 0; rg < 4; ++rg) {
                    int R = Rbase + rg;
                    if (R < N_NODES) {
                        if (c < 64) h0b[(size_t)R * 64 + c] = f2b(dn[rg] * acc[rg16][i][rg]);
                        else        res0[(size_t)R * 64 + (c - 64)] = gelu_exact(acc[rg16][i][rg] + br_c[i]);
                    }
                }
            }
        }
        __syncthreads();
    }
}

// ---------------- gather-aggregate over bf16 rows (proven 16-lane uint2 version) ----------------
// MODE 0: out[n][c] = gelu(acc*dn_in + b0[c]) + out[n][c]   (res0 in out, in-place)
// MODE 1: out[n][c] = acc*dn_in
template <int MODE>
__global__ __launch_bounds__(256) void k_agg(
    const int* __restrict__ row_start, const int* __restrict__ csr_src,
    const unsigned short* __restrict__ hb, const float* __restrict__ dn_in,
    const float* __restrict__ b0, float* __restrict__ out)
{
    int node = blockIdx.x * 4 + (threadIdx.x >> 6);
    int lane = threadIdx.x & 63;
    int sub = lane >> 4, q = lane & 15;
    int beg = row_start[node], end = row_start[node + 1];
    float a0 = 0.f, a1 = 0.f, a2 = 0.f, a3 = 0.f;
    for (int j = beg; j < end; j += 64) {
        int idx = j + lane;
        int eid = (idx < end) ? csr_src[idx] : 0;
        int cnt = end - j; if (cnt > 64) cnt = 64;
        for (int u = sub; u < cnt; u += 4) {
            int s = __shfl(eid, u);
            uint2 v = *(const uint2*)(hb + (size_t)s * 64 + q * 4);
            a0 += b2f((unsigned short)(v.x & 0xFFFFu));
            a1 += b2f((unsigned short)(v.x >> 16));
            a2 += b2f((unsigned short)(v.y & 0xFFFFu));
            a3 += b2f((unsigned short)(v.y >> 16));
        }
    }
    a0 += __shfl_xor(a0, 16); a0 += __shfl_xor(a0, 32);
    a1 += __shfl_xor(a1, 16); a1 += __shfl_xor(a1, 32);
    a2 += __shfl_xor(a2, 16); a2 += __shfl_xor(a2, 32);
    a3 += __shfl_xor(a3, 16); a3 += __shfl_xor(a3, 32);
    if (sub == 0) {
        float dn = dn_in[node];
        size_t o = (size_t)node * 64 + q * 4;
        if (MODE == 0) {
            float4 r = *(const float4*)(out + o);
            float4 wv;
            wv.x = gelu_exact(a0 * dn + b0[q * 4 + 0]) + r.x;
            wv.y = gelu_exact(a1 * dn + b0[q * 4 + 1]) + r.y;
            wv.z = gelu_exact(a2 * dn + b0[q * 4 + 2]) + r.z;
            wv.w = gelu_exact(a3 * dn + b0[q * 4 + 3]) + r.w;
            *(float4*)(out + o) = wv;
        } else {
            float4 wv = make_float4(a0 * dn, a1 * dn, a2 * dn, a3 * dn);
            *(float4*)(out + o) = wv;
        }
    }
}

// ---------------- BN stats (layer 0) ----------------
__global__ __launch_bounds__(256) void k_stats_partial(const float* __restrict__ x,
        double* __restrict__ psum, double* __restrict__ psumsq)
{
    int t = threadIdx.x;
    int c = t & 63, rq = t >> 6;
    int per = (N_NODES + SB - 1) / SB;
    int r0 = blockIdx.x * per;
    int r1 = r0 + per; if (r1 > N_NODES) r1 = N_NODES;
    double s = 0.0, s2 = 0.0;
    for (int r = r0 + rq; r < r1; r += 4) {
        float v = x[(size_t)r * 64 + c];
        s += v; s2 += (double)v * v;
    }
    __shared__ double ls[4][64], ls2[4][64];
    ls[rq][c] = s; ls2[rq][c] = s2;
    __syncthreads();
    if (t < 64) {
        double a = ls[0][t] + ls[1][t] + ls[2][t] + ls[3][t];
        double a2 = ls2[0][t] + ls2[1][t] + ls2[2][t] + ls2[3][t];
        psum[blockIdx.x * 64 + t] = a;
        psumsq[blockIdx.x * 64 + t] = a2;
    }
}

// parallel final (512 threads = 8 waves; compile-time trip count)
__global__ __launch_bounds__(512) void k_stats_final(const double* __restrict__ psum,
                              const double* __restrict__ psumsq,
                              const float* __restrict__ g, const float* __restrict__ be,
                              float* __restrict__ scale, float* __restrict__ shift)
{
    __shared__ double ls[8][64], ls2[8][64];
    int t = threadIdx.x, c = t & 63, gq = t >> 6;
    double s = 0.0, s2 = 0.0;
    for (int b = gq; b < SB; b += 8) {
        s += psum[b * 64 + c];
        s2 += psumsq[b * 64 + c];
    }
    ls[gq][c] = s; ls2[gq][c] = s2;
    __syncthreads();
    if (t < 64) {
        double a = 0.0, a2 = 0.0;
        for (int i = 0; i < 8; ++i) { a += ls[i][t]; a2 += ls2[i][t]; }
        double mean = a / N_NODES;
        double var = a2 / N_NODES - mean * mean;
        float inv = (float)(1.0 / sqrt(var + (double)EPS)) * g[t];
        scale[t] = inv;
        shift[t] = be[t] - (float)mean * inv;
    }
}

// f32-partial variant (layer 1, NTILE partials from k_gemm1)
__global__ __launch_bounds__(512) void k_stats_final_f32(const float* __restrict__ psum,
                                  const float* __restrict__ psumsq,
                                  const float* __restrict__ g, const float* __restrict__ be,
                                  float* __restrict__ scale, float* __restrict__ shift)
{
    __shared__ double ls[8][64], ls2[8][64];
    int t = threadIdx.x, c = t & 63, gq = t >> 6;
    double s = 0.0, s2 = 0.0;
    for (int b = gq; b < NTILE; b += 8) {
        s += (double)psum[b * 64 + c];
        s2 += (double)psumsq[b * 64 + c];
    }
    ls[gq][c] = s; ls2[gq][c] = s2;
    __syncthreads();
    if (t < 64) {
        double a = 0.0, a2 = 0.0;
        for (int i = 0; i < 8; ++i) { a += ls[i][t]; a2 += ls2[i][t]; }
        double mean = a / N_NODES;
        double var = a2 / N_NODES - mean * mean;
        float inv = (float)(1.0 / sqrt(var + (double)EPS)) * g[t];
        scale[t] = inv;
        shift[t] = be[t] - (float)mean * inv;
    }
}

// ---------------- h1b = bf16((scale*new0+shift)*dn_out) (4 elems/thread) ----------------
__global__ __launch_bounds__(256) void k_norm1(const float* __restrict__ scale,
                        const float* __restrict__ shift,
                        const float* __restrict__ dn_out,
                        const float* __restrict__ new0, unsigned short* __restrict__ h1b)
{
    int idx = blockIdx.x * 256 + threadIdx.x;   // one per 4 elements
    int r = idx >> 4, q = idx & 15;
    float dn = dn_out[r];
    float4 v = *(const float4*)(new0 + (size_t)r * 64 + q * 4);
    float4 sc = *(const float4*)(scale + q * 4);
    float4 sh = *(const float4*)(shift + q * 4);
    unsigned short h0 = f2b((sc.x * v.x + sh.x) * dn);
    unsigned short h1 = f2b((sc.y * v.y + sh.y) * dn);
    unsigned short h2 = f2b((sc.z * v.z + sh.z) * dn);
    unsigned short h3 = f2b((sc.w * v.w + sh.w) * dn);
    unsigned p0 = (unsigned)h0 | ((unsigned)h1 << 16);
    unsigned p1 = (unsigned)h2 | ((unsigned)h3 << 16);
    *(uint2*)(h1b + (size_t)r * 64 + q * 4) = make_uint2(p0, p1);
}

// ---------------- layer1 MFMA GEMM (column-split waves, grid = NTILE, fused BN stats) ----------------
// out = gelu(aggs@W1+b1) + gelu((scale0*new0+shift0)@Wr1+br1), in-place on aggs.
// wave w owns output cols w*16..w*16+15 (both W and R paths), all 64 rows.
__global__ __launch_bounds__(256) void k_gemm1(
    const float* __restrict__ aggs, const float* __restrict__ new0,
    const unsigned short* __restrict__ Wt1,
    const float* __restrict__ b1_, const float* __restrict__ br1,
    const float* __restrict__ scale0, const float* __restrict__ shift0,
    float* __restrict__ out_new,
    float* __restrict__ psum1, float* __restrict__ psumsq1)
{
    __shared__ unsigned short xa[64][72];   // stride 144B = 9 x 16B
    __shared__ unsigned short xb[64][72];
    __shared__ float cs[64], cs2[64];
    int t = threadIdx.x;
    int lane = t & 63;
    int w = t >> 6;
    int g = lane >> 4, r16 = lane & 15;
    int rr = t >> 2, q4 = t & 3;

    bf16x8 bW[2], bR[2];
    {
        int n = w * 16 + r16;
        for (int ks = 0; ks < 2; ++ks) {
            bW[ks] = *(const bf16x8*)(Wt1 + n * 64 + ks * 32 + g * 8);
            bR[ks] = *(const bf16x8*)(Wt1 + (64 + n) * 64 + ks * 32 + g * 8);
        }
    }
    float bias1 = b1_[w * 16 + r16];
    float biasr = br1[w * 16 + r16];
    float4 sc_[4], sh_[4];
    for (int i = 0; i < 4; ++i) {
        sc_[i] = *(const float4*)(scale0 + q4 * 16 + i * 4);
        sh_[i] = *(const float4*)(shift0 + q4 * 16 + i * 4);
    }
    float s_ = 0.f, s2_ = 0.f;

    if (t < 64) { cs[t] = 0.f; cs2[t] = 0.f; }

    for (int tile = blockIdx.x; tile < NTILE; tile += gridDim.x) {
        int row0 = tile * 64;
        {
            int R = row0 + rr;
            bool ok = (R < N_NODES);
            const float* pa = aggs + (size_t)R * 64 + q4 * 16;
            const float* pb = new0 + (size_t)R * 64 + q4 * 16;
            for (int i = 0; i < 4; ++i) {
                float4 va = ok ? *(const float4*)(pa + i * 4) : make_float4(0.f, 0.f, 0.f, 0.f);
                float4 vb = ok ? *(const float4*)(pb + i * 4) : make_float4(0.f, 0.f, 0.f, 0.f);
                vb.x = sc_[i].x * vb.x + sh_[i].x;
                vb.y = sc_[i].y * vb.y + sh_[i].y;
                vb.z = sc_[i].z * vb.z + sh_[i].z;
                vb.w = sc_[i].w * vb.w + sh_[i].w;
                unsigned pa0 = (unsigned)f2b(va.x) | ((unsigned)f2b(va.y) << 16);
                unsigned pa1 = (unsigned)f2b(va.z) | ((unsigned)f2b(va.w) << 16);
                unsigned pb0 = (unsigned)f2b(vb.x) | ((unsigned)f2b(vb.y) << 16);
                unsigned pb1 = (unsigned)f2b(vb.z) | ((unsigned)f2b(vb.w) << 16);
                *(uint2*)(&xa[rr][q4 * 16 + i * 4]) = make_uint2(pa0, pa1);
                *(uint2*)(&xb[rr][q4 * 16 + i * 4]) = make_uint2(pb0, pb1);
            }
        }
        __syncthreads();

        int c = w * 16 + r16;
        for (int rg16 = 0; rg16 < 4; ++rg16) {
            int arow = rg16 * 16 + r16;
            bf16x8 aA[2], aB[2];
            for (int ks = 0; ks < 2; ++ks) {
                aA[ks] = *(const bf16x8*)(&xa[arow][ks * 32 + g * 8]);
                aB[ks] = *(const bf16x8*)(&xb[arow][ks * 32 + g * 8]);
            }
            f32x4 accW = (f32x4){0.f, 0.f, 0.f, 0.f};
            f32x4 accR = (f32x4){0.f, 0.f, 0.f, 0.f};
            for (int ks = 0; ks < 2; ++ks) {
                accW = __builtin_amdgcn_mfma_f32_16x16x32_bf16(aA[ks], bW[ks], accW, 0, 0, 0);
                accR = __builtin_amdgcn_mfma_f32_16x16x32_bf16(aB[ks], bR[ks], accR, 0, 0, 0);
            }
            int Rbase = row0 + rg16 * 16 + g * 4;
            for (int rg = 0; rg < 4; ++rg) {
                int R = Rbase + rg;
                if (R < N_NODES) {
                    float v = gelu_exact(accW[rg] + bias1) + gelu_exact(accR[rg] + biasr);
                    out_new[(size_t)R * 64 + c] = v;
                    s_ += v;
                    s2_ += v * v;
                }
            }
        }
        __syncthreads();
    }

    // fused BN-stats partial reduce (cs was zeroed before first barrier)
    atomicAdd(&cs[w * 16 + r16], s_);
    atomicAdd(&cs2[w * 16 + r16], s2_);
    __syncthreads();
    if (t < 64) {
        psum1[blockIdx.x * 64 + t] = cs[t];
        psumsq1[blockIdx.x * 64 + t] = cs2[t];
    }
}

// ---------------- head ----------------
__global__ void k_final(const int* __restrict__ offsets,
                        const float* __restrict__ h2,
                        const float* __restrict__ scale, const float* __restrict__ shift,
                        const float* __restrict__ Wl, const float* __restrict__ bl,
                        float* __restrict__ out)
{
    __shared__ float xv[64];
    int g = blockIdx.x;
    int t = threadIdx.x;
    int row = offsets[g];
    if (t < 64) xv[t] = h2[(size_t)row * 64 + t] * scale[t] + shift[t];
    __syncthreads();
    if (t < N_CLS) {
        float s = bl[t];
        for (int k = 0; k < 64; ++k) s += xv[k] * Wl[k * N_CLS + t];
        out[g * N_CLS + t] = s;
    }
}

extern "C" void kernel_launch(void* const* d_in, const int* in_sizes, int n_in,
                              void* d_out, int out_size, void* d_ws, size_t ws_size,
                              hipStream_t stream)
{
    const float* feats = (const float*)d_in[0];
    const int* src     = (const int*)d_in[1];
    const int* dst     = (const int*)d_in[2];
    const int* offsets = (const int*)d_in[3];
    const float* W0  = (const float*)d_in[4];
    const float* b0  = (const float*)d_in[5];
    const float* Wr0 = (const float*)d_in[6];
    const float* br0 = (const float*)d_in[7];
    const float* g0  = (const float*)d_in[8];
    const float* be0 = (const float*)d_in[9];
    const float* W1  = (const float*)d_in[10];
    const float* b1  = (const float*)d_in[11];
    const float* Wr1 = (const float*)d_in[12];
    const float* br1 = (const float*)d_in[13];
    const float* g1  = (const float*)d_in[14];
    const float* be1 = (const float*)d_in[15];
    const float* Wl  = (const float*)d_in[16];
    const float* bl  = (const float*)d_in[17];
    float* out = (float*)d_out;

    char* ws = (char*)d_ws;
    size_t off = 0;
    auto alloc = [&](size_t bytes) -> void* {
        off = (off + 255) & ~(size_t)255;
        void* p = ws + off;
        off += bytes;
        return p;
    };

    const size_t NB = (size_t)N_NODES * HID * sizeof(float);  // 25.6MB
    unsigned short* Hb = (unsigned short*)alloc(NB / 2);  // h0b / h1b (bf16)
    float* B = (float*)alloc(NB);                         // res0 -> new0
    float* C = (float*)alloc(NB);                         // hist partials (early) / aggs -> new1
    unsigned* P = (unsigned*)C;                           // 16.8MB alias, dead before k_agg<1>
    unsigned short* Wt0 = (unsigned short*)alloc(128 * 128 * sizeof(unsigned short));
    unsigned short* Wt1 = (unsigned short*)alloc(128 * 64 * sizeof(unsigned short));
    int* cnt_in = (int*)alloc((size_t)N_NODES * sizeof(int));
    float* dn_out = (float*)alloc(N_NODES * sizeof(float));
    float* dn_in  = (float*)alloc(N_NODES * sizeof(float));
    int* bsum = (int*)alloc(SCAN_BLK * sizeof(int));
    int* bpre = (int*)alloc(SCAN_BLK * sizeof(int));
    int* row_start = (int*)alloc((SCAN_BLK * 256 + 1) * sizeof(int));
    int* csr_src   = (int*)alloc((size_t)N_EDGES * sizeof(int));
    double* psum   = (double*)alloc((size_t)SB * 64 * sizeof(double));
    double* psumsq = (double*)alloc((size_t)SB * 64 * sizeof(double));
    float* psum1   = (float*)alloc((size_t)NTILE * 64 * sizeof(float));
    float* psumsq1 = (float*)alloc((size_t)NTILE * 64 * sizeof(float));
    float* scale0 = (float*)alloc(64 * sizeof(float));
    float* shift0 = (float*)alloc(64 * sizeof(float));
    float* scale1 = (float*)alloc(64 * sizeof(float));
    float* shift1 = (float*)alloc(64 * sizeof(float));
    (void)ws_size; (void)n_in; (void)in_sizes; (void)out_size;

    // weight prep + degree histograms + CSR (reused by both layers)
    k_prep_w<<<64, 256, 0, stream>>>(W0, Wr0, W1, Wr1, Wt0, Wt1);
    k_hist<<<2 * HNR * HNC, 256, 0, stream>>>(src, dst, P);
    k_hist_reduce<<<HNR * HWORDS / 256, 256, 0, stream>>>(P, cnt_in, dn_in, dn_out);
    k_scan_reduce<<<SCAN_BLK, 256, 0, stream>>>(cnt_in, bsum);
    k_scan_bsum<<<1, 512, 0, stream>>>(bsum, bpre);
    k_scan_write<<<SCAN_BLK, 256, 0, stream>>>(cnt_in, bpre, row_start);
    k_fill2<<<FNR * HNC, 256, 0, stream>>>(src, dst, row_start, P, csr_src);

    // layer 0
    k_gemm0<<<NTILE, 256, 0, stream>>>(feats, Wt0, br0, dn_out, Hb, B);
    k_agg<0><<<N_NODES / 4, 256, 0, stream>>>(row_start, csr_src, Hb, dn_in, b0, B);
    k_stats_partial<<<SB, 256, 0, stream>>>(B, psum, psumsq);
    k_stats_final<<<1, 512, 0, stream>>>(psum, psumsq, g0, be0, scale0, shift0);
    k_norm1<<<(N_NODES * HID / 4) / 256, 256, 0, stream>>>(scale0, shift0, dn_out, B, Hb);

    // layer 1
    k_agg<1><<<N_NODES / 4, 256, 0, stream>>>(row_start, csr_src, Hb, dn_in, nullptr, C);
    k_gemm1<<<NTILE, 256, 0, stream>>>(C, B, Wt1, b1, br1, scale0, shift0, C, psum1, psumsq1);
    k_stats_final_f32<<<1, 512, 0, stream>>>(psum1, psumsq1, g1, be1, scale1, shift1);

    // head
    k_final<<<N_GRAPHS, 64, 0, stream>>>(offsets, C, scale1, shift1, Wl, bl, out);
}

// Round 15
// 274.922 us; speedup vs baseline: 1.2421x; 1.2421x over previous
//
#include <hip/hip_runtime.h>
#include <hip/hip_bf16.h>
#include <math.h>

#define N_NODES 100000
#define N_EDGES 1000000
#define N_GRAPHS 100
#define IN_F 128
#define HID 64
#define N_CLS 40
#define EPS 1e-5f
#define SB 512          // stats partial blocks (layer0)
#define SCAN_BLK 391    // 391*256 = 100096 >= N_NODES+1
#define NTILE 1563      // ceil(N_NODES/64); gemm grids + gemm1 stats partial count

// histogram geometry
#define HRANGE 32768            // nodes per range (2 per u32 word)
#define HNR 4                   // ranges: 4*32768 >= N_NODES
#define HNC 32                  // edge chunks
#define HWORDS (HRANGE / 2)     // 16384 u32 words = 64KB LDS
#define HESLICE (N_EDGES / HNC) // 31250

// fill geometry (sub-ranges of 4096 nodes; 24KB LDS)
#define FRANGE 4096
#define FNR 25                  // 25*4096 = 102400 >= N_NODES

typedef __attribute__((ext_vector_type(8))) short bf16x8;
typedef __attribute__((ext_vector_type(4))) float f32x4;

__device__ __forceinline__ float gelu_exact(float x) {
    return 0.5f * x * (1.0f + erff(x * 0.70710678118654752f));
}

__device__ __forceinline__ unsigned short f2b(float f) {  // f32 -> bf16 RNE
    unsigned u = __builtin_bit_cast(unsigned, f);
    return (unsigned short)((u + 0x7FFFu + ((u >> 16) & 1u)) >> 16);
}
__device__ __forceinline__ float b2f(unsigned short h) {
    unsigned u = ((unsigned)h) << 16;
    return __builtin_bit_cast(float, u);
}

// ---------------- weight prep: Wt0[n][k] bf16 (n<64:W0, else Wr0), Wt1 likewise
__global__ void k_prep_w(const float* __restrict__ W0, const float* __restrict__ Wr0,
                         const float* __restrict__ W1, const float* __restrict__ Wr1,
                         unsigned short* __restrict__ Wt0, unsigned short* __restrict__ Wt1) {
    int t = blockIdx.x * 256 + threadIdx.x;
    for (int idx = t; idx < 128 * 128; idx += gridDim.x * 256) {
        int n = idx >> 7, k = idx & 127;
        float v = (n < 64) ? W0[k * 64 + n] : Wr0[k * 64 + (n - 64)];
        Wt0[n * 128 + k] = f2b(v);
    }
    for (int idx = t; idx < 128 * 64; idx += gridDim.x * 256) {
        int n = idx >> 6, k = idx & 63;
        float v = (n < 64) ? W1[k * 64 + n] : Wr1[k * 64 + (n - 64)];
        Wt1[n * 64 + k] = f2b(v);
    }
}

// ---------------- LDS-privatized degree histogram (no global atomics) ----------------
__global__ __launch_bounds__(256) void k_hist(const int* __restrict__ src,
                                              const int* __restrict__ dst,
                                              unsigned* __restrict__ P) {
    __shared__ unsigned h[HWORDS];
    int t = threadIdx.x;
    int b = blockIdx.x;
    int chunk = b & (HNC - 1);
    int job = b >> 5;
    int range = job & (HNR - 1);
    const int* v = (job < HNR) ? dst : src;
    int base = range * HRANGE;
    for (int i = t; i < HWORDS; i += 256) h[i] = 0;
    __syncthreads();
    int e0 = chunk * HESLICE;
    for (int i = t; i < HESLICE / 2; i += 256) {
        uint2 d2 = *(const uint2*)(v + e0 + 2 * i);
        int o = (int)d2.x - base;
        if ((unsigned)o < HRANGE) atomicAdd(&h[o >> 1], 1u << ((o & 1) * 16));
        o = (int)d2.y - base;
        if ((unsigned)o < HRANGE) atomicAdd(&h[o >> 1], 1u << ((o & 1) * 16));
    }
    __syncthreads();
    unsigned* outp = P + (size_t)b * HWORDS;
    for (int i = t; i < HWORDS; i += 256) outp[i] = h[i];
}

// sum partials -> cnt_in, dn_in, dn_out; ALSO rewrite dst-partials in place as
// exclusive chunk-prefix (packed u16 add is carry-safe: per-node totals << 65536).
__global__ __launch_bounds__(256) void k_hist_reduce(unsigned* __restrict__ P,
                                                     int* __restrict__ cnt_in,
                                                     float* __restrict__ dn_in,
                                                     float* __restrict__ dn_out) {
    int w = blockIdx.x * 256 + threadIdx.x;   // 0 .. HNR*HWORDS-1 (65536)
    int range = w >> 14;
    int widx = w & (HWORDS - 1);
    unsigned* pin  = P + (size_t)(range * HNC) * HWORDS + widx;
    const unsigned* pout = P + (size_t)((HNR + range) * HNC) * HWORDS + widx;
    unsigned s_in = 0, s_out = 0;
    for (int c = 0; c < HNC; ++c) {
        unsigned v = pin[(size_t)c * HWORDS];
        pin[(size_t)c * HWORDS] = s_in;      // exclusive prefix along chunk axis
        s_in += v;
        s_out += pout[(size_t)c * HWORDS];
    }
    int n0 = range * HRANGE + widx * 2;
    unsigned ci0 = s_in & 0xFFFFu,  ci1 = s_in >> 16;
    unsigned co0 = s_out & 0xFFFFu, co1 = s_out >> 16;
    if (n0 < N_NODES) {
        cnt_in[n0] = (int)ci0;
        dn_in[n0]  = rsqrtf((float)(ci0 > 0 ? ci0 : 1));
        dn_out[n0] = rsqrtf((float)(co0 > 0 ? co0 : 1));
    }
    if (n0 + 1 < N_NODES) {
        cnt_in[n0 + 1] = (int)ci1;
        dn_in[n0 + 1]  = rsqrtf((float)(ci1 > 0 ? ci1 : 1));
        dn_out[n0 + 1] = rsqrtf((float)(co1 > 0 ? co1 : 1));
    }
}

// ---------------- CSR build ----------------
__global__ __launch_bounds__(256) void k_scan_reduce(const int* __restrict__ cnt,
                                                     int* __restrict__ bsum) {
    __shared__ int sh[256];
    int t = threadIdx.x;
    int i = blockIdx.x * 256 + t;
    int c = (i < N_NODES) ? cnt[i] : 0;
    sh[t] = c;
    __syncthreads();
    for (int d = 128; d > 0; d >>= 1) {
        if (t < d) sh[t] += sh[t + d];
        __syncthreads();
    }
    if (t == 0) bsum[blockIdx.x] = sh[0];
}

__global__ __launch_bounds__(512) void k_scan_bsum(const int* __restrict__ bsum,
                                                   int* __restrict__ bpre) {
    __shared__ int sh[512];
    int t = threadIdx.x;
    int v = (t < SCAN_BLK) ? bsum[t] : 0;
    sh[t] = v;
    __syncthreads();
    for (int d = 1; d < 512; d <<= 1) {
        int x = (t >= d) ? sh[t - d] : 0;
        __syncthreads();
        sh[t] += x;
        __syncthreads();
    }
    if (t < SCAN_BLK) bpre[t] = sh[t] - v;
}

__global__ __launch_bounds__(256) void k_scan_write(const int* __restrict__ cnt_in,
                                                    const int* __restrict__ bpre,
                                                    int* __restrict__ row_start) {
    __shared__ int sh[256];
    int t = threadIdx.x;
    int i = blockIdx.x * 256 + t;
    int c = (i < N_NODES) ? cnt_in[i] : 0;
    sh[t] = c;
    __syncthreads();
    for (int d = 1; d < 256; d <<= 1) {
        int v = (t >= d) ? sh[t - d] : 0;
        __syncthreads();
        sh[t] += v;
        __syncthreads();
    }
    int excl = sh[t] - c + bpre[blockIdx.x];
    if (i <= N_NODES) row_start[i] = excl;
}

// ---------------- atomic-free CSR fill (uint2 edge loads, unconditional) ----------------
__global__ __launch_bounds__(256) void k_fill2(const int* __restrict__ src,
                                               const int* __restrict__ dst,
                                               const int* __restrict__ row_start,
                                               const unsigned* __restrict__ Ppre,
                                               int* __restrict__ csr_src) {
    __shared__ unsigned base[FRANGE];       // 16 KB
    __shared__ unsigned curs[FRANGE / 2];   // 8 KB (packed u16 pairs)
    int t = threadIdx.x;
    int b = blockIdx.x;
    int c = b & (HNC - 1);
    int fr = b >> 5;
    int r = fr >> 3;                        // hist range (32768 nodes)
    int sub = fr & 7;                       // eighth within hist range
    int n0 = fr * FRANGE;
    const unsigned* pp = Ppre + (size_t)(r * HNC + c) * HWORDS + sub * (FRANGE / 2);
    for (int i = t; i < FRANGE / 2; i += 256) {
        unsigned pref = pp[i];
        int n = n0 + 2 * i;
        int2 rs = *(const int2*)(row_start + n);  // overread past N_NODES stays in ws; guarded
        base[2 * i]     = (n < N_NODES)     ? (unsigned)rs.x + (pref & 0xFFFFu) : 0u;
        base[2 * i + 1] = (n + 1 < N_NODES) ? (unsigned)rs.y + (pref >> 16)     : 0u;
        curs[i] = 0;
    }
    __syncthreads();
    int e0 = c * HESLICE;
    for (int i = t; i < HESLICE / 2; i += 256) {
        uint2 d2 = *(const uint2*)(dst + e0 + 2 * i);
        uint2 s2 = *(const uint2*)(src + e0 + 2 * i);
        int o0 = (int)d2.x - n0;
        if ((unsigned)o0 < FRANGE) {
            unsigned old = atomicAdd(&curs[o0 >> 1], 1u << ((o0 & 1) * 16));
            unsigned loc = (old >> ((o0 & 1) * 16)) & 0xFFFFu;
            csr_src[base[o0] + loc] = (int)s2.x;
        }
        int o1 = (int)d2.y - n0;
        if ((unsigned)o1 < FRANGE) {
            unsigned old = atomicAdd(&curs[o1 >> 1], 1u << ((o1 & 1) * 16));
            unsigned loc = (old >> ((o1 & 1) * 16)) & 0xFFFFu;
            csr_src[base[o1] + loc] = (int)s2.y;
        }
    }
}

// ---------------- layer0 MFMA GEMM (column-split waves, grid = NTILE) ----------------
// h0b = bf16(dn_out*(x@W0)), res0 = gelu(x@Wr0+br0)
// wave w owns cols w*32..w*32+31 (2 col-tiles), all 64 rows. bfrag = 32 VGPRs.
__global__ __launch_bounds__(256) void k_gemm0(
    const float* __restrict__ x, const unsigned short* __restrict__ Wt0,
    const float* __restrict__ br0, const float* __restrict__ dn_out,
    unsigned short* __restrict__ h0b, float* __restrict__ res0)
{
    __shared__ unsigned short xs[64][136];   // padded stride 272B
    int t = threadIdx.x;
    int lane = t & 63;
    int w = t >> 6;
    int g = lane >> 4, r16 = lane & 15;
    int rr = t >> 2, q4 = t & 3;

    bf16x8 bfrag[2][4];
    for (int i = 0; i < 2; ++i) {
        int n = (2 * w + i) * 16 + r16;
        for (int ks = 0; ks < 4; ++ks)
            bfrag[i][ks] = *(const bf16x8*)(Wt0 + n * 128 + ks * 32 + g * 8);
    }
    float br_c[2];
    for (int i = 0; i < 2; ++i) {
        int c = (2 * w + i) * 16 + r16;
        br_c[i] = (c >= 64) ? br0[c - 64] : 0.f;
    }

    for (int tile = blockIdx.x; tile < NTILE; tile += gridDim.x) {
        int row0 = tile * 64;
        {
            int R = row0 + rr;
            bool ok = (R < N_NODES);
            const float* xp = x + (size_t)R * IN_F + q4 * 32;
            for (int i = 0; i < 8; ++i) {
                float4 v = ok ? *(const float4*)(xp + i * 4) : make_float4(0.f, 0.f, 0.f, 0.f);
                unsigned p0 = (unsigned)f2b(v.x) | ((unsigned)f2b(v.y) << 16);
                unsigned p1 = (unsigned)f2b(v.z) | ((unsigned)f2b(v.w) << 16);
                *(uint2*)(&xs[rr][q4 * 32 + i * 4]) = make_uint2(p0, p1);
            }
        }
        __syncthreads();

        f32x4 acc[4][2];
        for (int rg16 = 0; rg16 < 4; ++rg16)
            for (int i = 0; i < 2; ++i)
                acc[rg16][i] = (f32x4){0.f, 0.f, 0.f, 0.f};

        for (int rg16 = 0; rg16 < 4; ++rg16) {
            int arow = rg16 * 16 + r16;
            bf16x8 a[4];
            for (int ks = 0; ks < 4; ++ks)
                a[ks] = *(const bf16x8*)(&xs[arow][ks * 32 + g * 8]);
            for (int ks = 0; ks < 4; ++ks)
                for (int i = 0; i < 2; ++i)
                    acc[rg16][i] = __builtin_amdgcn_mfma_f32_16x16x32_bf16(a[ks], bfrag[i][ks], acc[rg16][i], 0, 0, 0);
        }

        for (int rg16 = 0; rg16 < 4; ++rg16) {
            int Rbase = row0 + rg16 * 16 + g * 4;
            float dn[4];
            for (int rg = 0; rg < 4; ++rg) {
                int R = Rbase + rg;
                dn[rg] = (R < N_NODES) ? dn_out[R] : 0.f;
            }
            for (int i = 0; i < 2; ++i) {
                int c = (2 * w + i) * 16 + r16;
                for (int rg = 0; rg < 4; ++rg) {
                    int R = Rbase + rg;
                    if (R < N_NODES) {
                        if (c < 64) h0b[(size_t)R * 64 + c] = f2b(dn[rg] * acc[rg16][i][rg]);
                        else        res0[(size_t)R * 64 + (c - 64)] = gelu_exact(acc[rg16][i][rg] + br_c[i]);
                    }
                }
            }
        }
        __syncthreads();
    }
}

// ---------------- gather-aggregate over bf16 rows (proven 16-lane uint2 version) ----------------
// MODE 0: out[n][c] = gelu(acc*dn_in + b0[c]) + out[n][c]   (res0 in out, in-place)
// MODE 1: out[n][c] = acc*dn_in
template <int MODE>
__global__ __launch_bounds__(256) void k_agg(
    const int* __restrict__ row_start, const int* __restrict__ csr_src,
    const unsigned short* __restrict__ hb, const float* __restrict__ dn_in,
    const float* __restrict__ b0, float* __restrict__ out)
{
    int node = blockIdx.x * 4 + (threadIdx.x >> 6);
    int lane = threadIdx.x & 63;
    int sub = lane >> 4, q = lane & 15;
    int beg = row_start[node], end = row_start[node + 1];
    float a0 = 0.f, a1 = 0.f, a2 = 0.f, a3 = 0.f;
    for (int j = beg; j < end; j += 64) {
        int idx = j + lane;
        int eid = (idx < end) ? csr_src[idx] : 0;
        int cnt = end - j; if (cnt > 64) cnt = 64;
        for (int u = sub; u < cnt; u += 4) {
            int s = __shfl(eid, u);
            uint2 v = *(const uint2*)(hb + (size_t)s * 64 + q * 4);
            a0 += b2f((unsigned short)(v.x & 0xFFFFu));
            a1 += b2f((unsigned short)(v.x >> 16));
            a2 += b2f((unsigned short)(v.y & 0xFFFFu));
            a3 += b2f((unsigned short)(v.y >> 16));
        }
    }
    a0 += __shfl_xor(a0, 16); a0 += __shfl_xor(a0, 32);
    a1 += __shfl_xor(a1, 16); a1 += __shfl_xor(a1, 32);
    a2 += __shfl_xor(a2, 16); a2 += __shfl_xor(a2, 32);
    a3 += __shfl_xor(a3, 16); a3 += __shfl_xor(a3, 32);
    if (sub == 0) {
        float dn = dn_in[node];
        size_t o = (size_t)node * 64 + q * 4;
        if (MODE == 0) {
            float4 r = *(const float4*)(out + o);
            float4 wv;
            wv.x = gelu_exact(a0 * dn + b0[q * 4 + 0]) + r.x;
            wv.y = gelu_exact(a1 * dn + b0[q * 4 + 1]) + r.y;
            wv.z = gelu_exact(a2 * dn + b0[q * 4 + 2]) + r.z;
            wv.w = gelu_exact(a3 * dn + b0[q * 4 + 3]) + r.w;
            *(float4*)(out + o) = wv;
        } else {
            float4 wv = make_float4(a0 * dn, a1 * dn, a2 * dn, a3 * dn);
            *(float4*)(out + o) = wv;
        }
    }
}

// ---------------- BN stats (layer 0 partials) ----------------
__global__ __launch_bounds__(256) void k_stats_partial(const float* __restrict__ x,
        double* __restrict__ psum, double* __restrict__ psumsq)
{
    int t = threadIdx.x;
    int c = t & 63, rq = t >> 6;
    int per = (N_NODES + SB - 1) / SB;
    int r0 = blockIdx.x * per;
    int r1 = r0 + per; if (r1 > N_NODES) r1 = N_NODES;
    double s = 0.0, s2 = 0.0;
    for (int r = r0 + rq; r < r1; r += 4) {
        float v = x[(size_t)r * 64 + c];
        s += v; s2 += (double)v * v;
    }
    __shared__ double ls[4][64], ls2[4][64];
    ls[rq][c] = s; ls2[rq][c] = s2;
    __syncthreads();
    if (t < 64) {
        double a = ls[0][t] + ls[1][t] + ls[2][t] + ls[3][t];
        double a2 = ls2[0][t] + ls2[1][t] + ls2[2][t] + ls2[3][t];
        psum[blockIdx.x * 64 + t] = a;
        psumsq[blockIdx.x * 64 + t] = a2;
    }
}

// ---------------- two-stage column reduce: 64 blocks, one per column ----------------
template <typename T, int NB>
__global__ __launch_bounds__(256) void k_colred(const T* __restrict__ ps, const T* __restrict__ ps2,
                                                double* __restrict__ ds, double* __restrict__ ds2) {
    __shared__ double l1[256], l2[256];
    int c = blockIdx.x;  // 0..63
    int t = threadIdx.x;
    double s = 0.0, s2 = 0.0;
    for (int b = t; b < NB; b += 256) {
        s += (double)ps[(size_t)b * 64 + c];
        s2 += (double)ps2[(size_t)b * 64 + c];
    }
    l1[t] = s; l2[t] = s2;
    __syncthreads();
    for (int d = 128; d > 0; d >>= 1) {
        if (t < d) { l1[t] += l1[t + d]; l2[t] += l2[t + d]; }
        __syncthreads();
    }
    if (t == 0) { ds[c] = l1[0]; ds2[c] = l2[0]; }
}

__global__ void k_bn_final(const double* __restrict__ ds, const double* __restrict__ ds2,
                           const float* __restrict__ g, const float* __restrict__ be,
                           float* __restrict__ scale, float* __restrict__ shift) {
    int c = threadIdx.x;
    if (c < 64) {
        double mean = ds[c] / N_NODES;
        double var = ds2[c] / N_NODES - mean * mean;
        float inv = (float)(1.0 / sqrt(var + (double)EPS)) * g[c];
        scale[c] = inv;
        shift[c] = be[c] - (float)mean * inv;
    }
}

// ---------------- h1b = bf16((scale*new0+shift)*dn_out) (4 elems/thread) ----------------
__global__ __launch_bounds__(256) void k_norm1(const float* __restrict__ scale,
                        const float* __restrict__ shift,
                        const float* __restrict__ dn_out,
                        const float* __restrict__ new0, unsigned short* __restrict__ h1b)
{
    int idx = blockIdx.x * 256 + threadIdx.x;   // one per 4 elements
    int r = idx >> 4, q = idx & 15;
    float dn = dn_out[r];
    float4 v = *(const float4*)(new0 + (size_t)r * 64 + q * 4);
    float4 sc = *(const float4*)(scale + q * 4);
    float4 sh = *(const float4*)(shift + q * 4);
    unsigned short h0 = f2b((sc.x * v.x + sh.x) * dn);
    unsigned short h1 = f2b((sc.y * v.y + sh.y) * dn);
    unsigned short h2 = f2b((sc.z * v.z + sh.z) * dn);
    unsigned short h3 = f2b((sc.w * v.w + sh.w) * dn);
    unsigned p0 = (unsigned)h0 | ((unsigned)h1 << 16);
    unsigned p1 = (unsigned)h2 | ((unsigned)h3 << 16);
    *(uint2*)(h1b + (size_t)r * 64 + q * 4) = make_uint2(p0, p1);
}

// ---------------- layer1 MFMA GEMM (column-split waves, grid = NTILE, fused BN stats) ----------------
// out = gelu(aggs@W1+b1) + gelu((scale0*new0+shift0)@Wr1+br1), in-place on aggs.
// wave w owns output cols w*16..w*16+15 (both W and R paths), all 64 rows.
__global__ __launch_bounds__(256) void k_gemm1(
    const float* __restrict__ aggs, const float* __restrict__ new0,
    const unsigned short* __restrict__ Wt1,
    const float* __restrict__ b1_, const float* __restrict__ br1,
    const float* __restrict__ scale0, const float* __restrict__ shift0,
    float* __restrict__ out_new,
    float* __restrict__ psum1, float* __restrict__ psumsq1)
{
    __shared__ unsigned short xa[64][72];   // stride 144B = 9 x 16B
    __shared__ unsigned short xb[64][72];
    __shared__ float cs[64], cs2[64];
    int t = threadIdx.x;
    int lane = t & 63;
    int w = t >> 6;
    int g = lane >> 4, r16 = lane & 15;
    int rr = t >> 2, q4 = t & 3;

    bf16x8 bW[2], bR[2];
    {
        int n = w * 16 + r16;
        for (int ks = 0; ks < 2; ++ks) {
            bW[ks] = *(const bf16x8*)(Wt1 + n * 64 + ks * 32 + g * 8);
            bR[ks] = *(const bf16x8*)(Wt1 + (64 + n) * 64 + ks * 32 + g * 8);
        }
    }
    float bias1 = b1_[w * 16 + r16];
    float biasr = br1[w * 16 + r16];
    float4 sc_[4], sh_[4];
    for (int i = 0; i < 4; ++i) {
        sc_[i] = *(const float4*)(scale0 + q4 * 16 + i * 4);
        sh_[i] = *(const float4*)(shift0 + q4 * 16 + i * 4);
    }
    float s_ = 0.f, s2_ = 0.f;

    if (t < 64) { cs[t] = 0.f; cs2[t] = 0.f; }

    for (int tile = blockIdx.x; tile < NTILE; tile += gridDim.x) {
        int row0 = tile * 64;
        {
            int R = row0 + rr;
            bool ok = (R < N_NODES);
            const float* pa = aggs + (size_t)R * 64 + q4 * 16;
            const float* pb = new0 + (size_t)R * 64 + q4 * 16;
            for (int i = 0; i < 4; ++i) {
                float4 va = ok ? *(const float4*)(pa + i * 4) : make_float4(0.f, 0.f, 0.f, 0.f);
                float4 vb = ok ? *(const float4*)(pb + i * 4) : make_float4(0.f, 0.f, 0.f, 0.f);
                vb.x = sc_[i].x * vb.x + sh_[i].x;
                vb.y = sc_[i].y * vb.y + sh_[i].y;
                vb.z = sc_[i].z * vb.z + sh_[i].z;
                vb.w = sc_[i].w * vb.w + sh_[i].w;
                unsigned pa0 = (unsigned)f2b(va.x) | ((unsigned)f2b(va.y) << 16);
                unsigned pa1 = (unsigned)f2b(va.z) | ((unsigned)f2b(va.w) << 16);
                unsigned pb0 = (unsigned)f2b(vb.x) | ((unsigned)f2b(vb.y) << 16);
                unsigned pb1 = (unsigned)f2b(vb.z) | ((unsigned)f2b(vb.w) << 16);
                *(uint2*)(&xa[rr][q4 * 16 + i * 4]) = make_uint2(pa0, pa1);
                *(uint2*)(&xb[rr][q4 * 16 + i * 4]) = make_uint2(pb0, pb1);
            }
        }
        __syncthreads();

        int c = w * 16 + r16;
        for (int rg16 = 0; rg16 < 4; ++rg16) {
            int arow = rg16 * 16 + r16;
            bf16x8 aA[2], aB[2];
            for (int ks = 0; ks < 2; ++ks) {
                aA[ks] = *(const bf16x8*)(&xa[arow][ks * 32 + g * 8]);
                aB[ks] = *(const bf16x8*)(&xb[arow][ks * 32 + g * 8]);
            }
            f32x4 accW = (f32x4){0.f, 0.f, 0.f, 0.f};
            f32x4 accR = (f32x4){0.f, 0.f, 0.f, 0.f};
            for (int ks = 0; ks < 2; ++ks) {
                accW = __builtin_amdgcn_mfma_f32_16x16x32_bf16(aA[ks], bW[ks], accW, 0, 0, 0);
                accR = __builtin_amdgcn_mfma_f32_16x16x32_bf16(aB[ks], bR[ks], accR, 0, 0, 0);
            }
            int Rbase = row0 + rg16 * 16 + g * 4;
            for (int rg = 0; rg < 4; ++rg) {
                int R = Rbase + rg;
                if (R < N_NODES) {
                    float v = gelu_exact(accW[rg] + bias1) + gelu_exact(accR[rg] + biasr);
                    out_new[(size_t)R * 64 + c] = v;
                    s_ += v;
                    s2_ += v * v;
                }
            }
        }
        __syncthreads();
    }

    // fused BN-stats partial reduce (cs was zeroed before first barrier)
    atomicAdd(&cs[w * 16 + r16], s_);
    atomicAdd(&cs2[w * 16 + r16], s2_);
    __syncthreads();
    if (t < 64) {
        psum1[blockIdx.x * 64 + t] = cs[t];
        psumsq1[blockIdx.x * 64 + t] = cs2[t];
    }
}

// ---------------- head ----------------
__global__ void k_final(const int* __restrict__ offsets,
                        const float* __restrict__ h2,
                        const float* __restrict__ scale, const float* __restrict__ shift,
                        const float* __restrict__ Wl, const float* __restrict__ bl,
                        float* __restrict__ out)
{
    __shared__ float xv[64];
    int g = blockIdx.x;
    int t = threadIdx.x;
    int row = offsets[g];
    if (t < 64) xv[t] = h2[(size_t)row * 64 + t] * scale[t] + shift[t];
    __syncthreads();
    if (t < N_CLS) {
        float s = bl[t];
        for (int k = 0; k < 64; ++k) s += xv[k] * Wl[k * N_CLS + t];
        out[g * N_CLS + t] = s;
    }
}

extern "C" void kernel_launch(void* const* d_in, const int* in_sizes, int n_in,
                              void* d_out, int out_size, void* d_ws, size_t ws_size,
                              hipStream_t stream)
{
    const float* feats = (const float*)d_in[0];
    const int* src     = (const int*)d_in[1];
    const int* dst     = (const int*)d_in[2];
    const int* offsets = (const int*)d_in[3];
    const float* W0  = (const float*)d_in[4];
    const float* b0  = (const float*)d_in[5];
    const float* Wr0 = (const float*)d_in[6];
    const float* br0 = (const float*)d_in[7];
    const float* g0  = (const float*)d_in[8];
    const float* be0 = (const float*)d_in[9];
    const float* W1  = (const float*)d_in[10];
    const float* b1  = (const float*)d_in[11];
    const float* Wr1 = (const float*)d_in[12];
    const float* br1 = (const float*)d_in[13];
    const float* g1  = (const float*)d_in[14];
    const float* be1 = (const float*)d_in[15];
    const float* Wl  = (const float*)d_in[16];
    const float* bl  = (const float*)d_in[17];
    float* out = (float*)d_out;

    char* ws = (char*)d_ws;
    size_t off = 0;
    auto alloc = [&](size_t bytes) -> void* {
        off = (off + 255) & ~(size_t)255;
        void* p = ws + off;
        off += bytes;
        return p;
    };

    const size_t NB = (size_t)N_NODES * HID * sizeof(float);  // 25.6MB
    unsigned short* Hb = (unsigned short*)alloc(NB / 2);  // h0b / h1b (bf16)
    float* B = (float*)alloc(NB);                         // res0 -> new0
    float* C = (float*)alloc(NB);                         // hist partials (early) / aggs -> new1
    unsigned* P = (unsigned*)C;                           // 16.8MB alias, dead before k_agg<1>
    unsigned short* Wt0 = (unsigned short*)alloc(128 * 128 * sizeof(unsigned short));
    unsigned short* Wt1 = (unsigned short*)alloc(128 * 64 * sizeof(unsigned short));
    int* cnt_in = (int*)alloc((size_t)N_NODES * sizeof(int));
    float* dn_out = (float*)alloc(N_NODES * sizeof(float));
    float* dn_in  = (float*)alloc(N_NODES * sizeof(float));
    int* bsum = (int*)alloc(SCAN_BLK * sizeof(int));
    int* bpre = (int*)alloc(SCAN_BLK * sizeof(int));
    int* row_start = (int*)alloc((SCAN_BLK * 256 + 1) * sizeof(int));
    int* csr_src   = (int*)alloc((size_t)N_EDGES * sizeof(int));
    double* psum   = (double*)alloc((size_t)SB * 64 * sizeof(double));
    double* psumsq = (double*)alloc((size_t)SB * 64 * sizeof(double));
    float* psum1   = (float*)alloc((size_t)NTILE * 64 * sizeof(float));
    float* psumsq1 = (float*)alloc((size_t)NTILE * 64 * sizeof(float));
    double* dsum   = (double*)alloc(64 * sizeof(double));
    double* dsumsq = (double*)alloc(64 * sizeof(double));
    float* scale0 = (float*)alloc(64 * sizeof(float));
    float* shift0 = (float*)alloc(64 * sizeof(float));
    float* scale1 = (float*)alloc(64 * sizeof(float));
    float* shift1 = (float*)alloc(64 * sizeof(float));
    (void)ws_size; (void)n_in; (void)in_sizes; (void)out_size;

    // weight prep + degree histograms + CSR (reused by both layers)
    k_prep_w<<<64, 256, 0, stream>>>(W0, Wr0, W1, Wr1, Wt0, Wt1);
    k_hist<<<2 * HNR * HNC, 256, 0, stream>>>(src, dst, P);
    k_hist_reduce<<<HNR * HWORDS / 256, 256, 0, stream>>>(P, cnt_in, dn_in, dn_out);
    k_scan_reduce<<<SCAN_BLK, 256, 0, stream>>>(cnt_in, bsum);
    k_scan_bsum<<<1, 512, 0, stream>>>(bsum, bpre);
    k_scan_write<<<SCAN_BLK, 256, 0, stream>>>(cnt_in, bpre, row_start);
    k_fill2<<<FNR * HNC, 256, 0, stream>>>(src, dst, row_start, P, csr_src);

    // layer 0
    k_gemm0<<<NTILE, 256, 0, stream>>>(feats, Wt0, br0, dn_out, Hb, B);
    k_agg<0><<<N_NODES / 4, 256, 0, stream>>>(row_start, csr_src, Hb, dn_in, b0, B);
    k_stats_partial<<<SB, 256, 0, stream>>>(B, psum, psumsq);
    k_colred<double, SB><<<64, 256, 0, stream>>>(psum, psumsq, dsum, dsumsq);
    k_bn_final<<<1, 64, 0, stream>>>(dsum, dsumsq, g0, be0, scale0, shift0);
    k_norm1<<<(N_NODES * HID / 4) / 256, 256, 0, stream>>>(scale0, shift0, dn_out, B, Hb);

    // layer 1
    k_agg<1><<<N_NODES / 4, 256, 0, stream>>>(row_start, csr_src, Hb, dn_in, nullptr, C);
    k_gemm1<<<NTILE, 256, 0, stream>>>(C, B, Wt1, b1, br1, scale0, shift0, C, psum1, psumsq1);
    k_colred<float, NTILE><<<64, 256, 0, stream>>>(psum1, psumsq1, dsum, dsumsq);
    k_bn_final<<<1, 64, 0, stream>>>(dsum, dsumsq, g1, be1, scale1, shift1);

    // head
    k_final<<<N_GRAPHS, 64, 0, stream>>>(offsets, C, scale1, shift1, Wl, bl, out);
}

// Round 17
// 264.864 us; speedup vs baseline: 1.2893x; 1.0380x over previous
//
#include <hip/hip_runtime.h>
#include <hip/hip_bf16.h>
#include <math.h>

#define N_NODES 100000
#define N_EDGES 1000000
#define N_GRAPHS 100
#define IN_F 128
#define HID 64
#define N_CLS 40
#define EPS 1e-5f
#define SB 512          // stats partial blocks (layer0)
#define SCAN_BLK 391    // 391*256 = 100096 >= N_NODES+1
#define NTILE 1563      // ceil(N_NODES/64); gemm grids + gemm1 stats partial count

// histogram geometry
#define HRANGE 32768            // nodes per range (2 per u32 word)
#define HNR 4                   // ranges: 4*32768 >= N_NODES
#define HNC 32                  // edge chunks
#define HWORDS (HRANGE / 2)     // 16384 u32 words = 64KB LDS
#define HESLICE (N_EDGES / HNC) // 31250

// fill geometry (sub-ranges of 4096 nodes; 24KB LDS)
#define FRANGE 4096
#define FNR 25                  // 25*4096 = 102400 >= N_NODES

typedef __attribute__((ext_vector_type(8))) short bf16x8;
typedef __attribute__((ext_vector_type(4))) float f32x4;

__device__ __forceinline__ float gelu_exact(float x) {
    return 0.5f * x * (1.0f + erff(x * 0.70710678118654752f));
}

__device__ __forceinline__ unsigned short f2b(float f) {  // f32 -> bf16 RNE
    unsigned u = __builtin_bit_cast(unsigned, f);
    return (unsigned short)((u + 0x7FFFu + ((u >> 16) & 1u)) >> 16);
}
__device__ __forceinline__ float b2f(unsigned short h) {
    unsigned u = ((unsigned)h) << 16;
    return __builtin_bit_cast(float, u);
}

// ---------------- weight prep: Wt0[n][k] bf16 (n<64:W0, else Wr0), Wt1 likewise
__global__ void k_prep_w(const float* __restrict__ W0, const float* __restrict__ Wr0,
                         const float* __restrict__ W1, const float* __restrict__ Wr1,
                         unsigned short* __restrict__ Wt0, unsigned short* __restrict__ Wt1) {
    int t = blockIdx.x * 256 + threadIdx.x;
    for (int idx = t; idx < 128 * 128; idx += gridDim.x * 256) {
        int n = idx >> 7, k = idx & 127;
        float v = (n < 64) ? W0[k * 64 + n] : Wr0[k * 64 + (n - 64)];
        Wt0[n * 128 + k] = f2b(v);
    }
    for (int idx = t; idx < 128 * 64; idx += gridDim.x * 256) {
        int n = idx >> 6, k = idx & 63;
        float v = (n < 64) ? W1[k * 64 + n] : Wr1[k * 64 + (n - 64)];
        Wt1[n * 64 + k] = f2b(v);
    }
}

// ---------------- LDS-privatized degree histogram (no global atomics) ----------------
__global__ __launch_bounds__(256) void k_hist(const int* __restrict__ src,
                                              const int* __restrict__ dst,
                                              unsigned* __restrict__ P) {
    __shared__ unsigned h[HWORDS];
    int t = threadIdx.x;
    int b = blockIdx.x;
    int chunk = b & (HNC - 1);
    int job = b >> 5;
    int range = job & (HNR - 1);
    const int* v = (job < HNR) ? dst : src;
    int base = range * HRANGE;
    for (int i = t; i < HWORDS; i += 256) h[i] = 0;
    __syncthreads();
    int e0 = chunk * HESLICE;
    for (int i = t; i < HESLICE / 2; i += 256) {
        uint2 d2 = *(const uint2*)(v + e0 + 2 * i);
        int o = (int)d2.x - base;
        if ((unsigned)o < HRANGE) atomicAdd(&h[o >> 1], 1u << ((o & 1) * 16));
        o = (int)d2.y - base;
        if ((unsigned)o < HRANGE) atomicAdd(&h[o >> 1], 1u << ((o & 1) * 16));
    }
    __syncthreads();
    unsigned* outp = P + (size_t)b * HWORDS;
    for (int i = t; i < HWORDS; i += 256) outp[i] = h[i];
}

// sum partials -> cnt_in, dn_in, dn_out; ALSO rewrite dst-partials in place as
// exclusive chunk-prefix (packed u16 add is carry-safe: per-node totals << 65536).
__global__ __launch_bounds__(256) void k_hist_reduce(unsigned* __restrict__ P,
                                                     int* __restrict__ cnt_in,
                                                     float* __restrict__ dn_in,
                                                     float* __restrict__ dn_out) {
    int w = blockIdx.x * 256 + threadIdx.x;   // 0 .. HNR*HWORDS-1 (65536)
    int range = w >> 14;
    int widx = w & (HWORDS - 1);
    unsigned* pin  = P + (size_t)(range * HNC) * HWORDS + widx;
    const unsigned* pout = P + (size_t)((HNR + range) * HNC) * HWORDS + widx;
    unsigned s_in = 0, s_out = 0;
    for (int c = 0; c < HNC; ++c) {
        unsigned v = pin[(size_t)c * HWORDS];
        pin[(size_t)c * HWORDS] = s_in;      // exclusive prefix along chunk axis
        s_in += v;
        s_out += pout[(size_t)c * HWORDS];
    }
    int n0 = range * HRANGE + widx * 2;
    unsigned ci0 = s_in & 0xFFFFu,  ci1 = s_in >> 16;
    unsigned co0 = s_out & 0xFFFFu, co1 = s_out >> 16;
    if (n0 < N_NODES) {
        cnt_in[n0] = (int)ci0;
        dn_in[n0]  = rsqrtf((float)(ci0 > 0 ? ci0 : 1));
        dn_out[n0] = rsqrtf((float)(co0 > 0 ? co0 : 1));
    }
    if (n0 + 1 < N_NODES) {
        cnt_in[n0 + 1] = (int)ci1;
        dn_in[n0 + 1]  = rsqrtf((float)(ci1 > 0 ? ci1 : 1));
        dn_out[n0 + 1] = rsqrtf((float)(co1 > 0 ? co1 : 1));
    }
}

// ---------------- CSR build ----------------
__global__ __launch_bounds__(256) void k_scan_reduce(const int* __restrict__ cnt,
                                                     int* __restrict__ bsum) {
    __shared__ int sh[256];
    int t = threadIdx.x;
    int i = blockIdx.x * 256 + t;
    int c = (i < N_NODES) ? cnt[i] : 0;
    sh[t] = c;
    __syncthreads();
    for (int d = 128; d > 0; d >>= 1) {
        if (t < d) sh[t] += sh[t + d];
        __syncthreads();
    }
    if (t == 0) bsum[blockIdx.x] = sh[0];
}

__global__ __launch_bounds__(512) void k_scan_bsum(const int* __restrict__ bsum,
                                                   int* __restrict__ bpre) {
    __shared__ int sh[512];
    int t = threadIdx.x;
    int v = (t < SCAN_BLK) ? bsum[t] : 0;
    sh[t] = v;
    __syncthreads();
    for (int d = 1; d < 512; d <<= 1) {
        int x = (t >= d) ? sh[t - d] : 0;
        __syncthreads();
        sh[t] += x;
        __syncthreads();
    }
    if (t < SCAN_BLK) bpre[t] = sh[t] - v;
}

__global__ __launch_bounds__(256) void k_scan_write(const int* __restrict__ cnt_in,
                                                    const int* __restrict__ bpre,
                                                    int* __restrict__ row_start) {
    __shared__ int sh[256];
    int t = threadIdx.x;
    int i = blockIdx.x * 256 + t;
    int c = (i < N_NODES) ? cnt_in[i] : 0;
    sh[t] = c;
    __syncthreads();
    for (int d = 1; d < 256; d <<= 1) {
        int v = (t >= d) ? sh[t - d] : 0;
        __syncthreads();
        sh[t] += v;
        __syncthreads();
    }
    int excl = sh[t] - c + bpre[blockIdx.x];
    if (i <= N_NODES) row_start[i] = excl;
}

// ---------------- atomic-free CSR fill (uint2 edge loads, unconditional) ----------------
__global__ __launch_bounds__(256) void k_fill2(const int* __restrict__ src,
                                               const int* __restrict__ dst,
                                               const int* __restrict__ row_start,
                                               const unsigned* __restrict__ Ppre,
                                               int* __restrict__ csr_src) {
    __shared__ unsigned base[FRANGE];       // 16 KB
    __shared__ unsigned curs[FRANGE / 2];   // 8 KB (packed u16 pairs)
    int t = threadIdx.x;
    int b = blockIdx.x;
    int c = b & (HNC - 1);
    int fr = b >> 5;
    int r = fr >> 3;                        // hist range (32768 nodes)
    int sub = fr & 7;                       // eighth within hist range
    int n0 = fr * FRANGE;
    const unsigned* pp = Ppre + (size_t)(r * HNC + c) * HWORDS + sub * (FRANGE / 2);
    for (int i = t; i < FRANGE / 2; i += 256) {
        unsigned pref = pp[i];
        int n = n0 + 2 * i;
        int2 rs = *(const int2*)(row_start + n);  // overread past N_NODES stays in ws; guarded
        base[2 * i]     = (n < N_NODES)     ? (unsigned)rs.x + (pref & 0xFFFFu) : 0u;
        base[2 * i + 1] = (n + 1 < N_NODES) ? (unsigned)rs.y + (pref >> 16)     : 0u;
        curs[i] = 0;
    }
    __syncthreads();
    int e0 = c * HESLICE;
    for (int i = t; i < HESLICE / 2; i += 256) {
        uint2 d2 = *(const uint2*)(dst + e0 + 2 * i);
        uint2 s2 = *(const uint2*)(src + e0 + 2 * i);
        int o0 = (int)d2.x - n0;
        if ((unsigned)o0 < FRANGE) {
            unsigned old = atomicAdd(&curs[o0 >> 1], 1u << ((o0 & 1) * 16));
            unsigned loc = (old >> ((o0 & 1) * 16)) & 0xFFFFu;
            csr_src[base[o0] + loc] = (int)s2.x;
        }
        int o1 = (int)d2.y - n0;
        if ((unsigned)o1 < FRANGE) {
            unsigned old = atomicAdd(&curs[o1 >> 1], 1u << ((o1 & 1) * 16));
            unsigned loc = (old >> ((o1 & 1) * 16)) & 0xFFFFu;
            csr_src[base[o1] + loc] = (int)s2.y;
        }
    }
}

// ---------------- layer0 MFMA GEMM (column-split waves, grid = NTILE) ----------------
// h0b = bf16(dn_out*(x@W0)), res0 = gelu(x@Wr0+br0)
// wave w owns cols w*32..w*32+31 (2 col-tiles), all 64 rows. bfrag = 32 VGPRs.
__global__ __launch_bounds__(256) void k_gemm0(
    const float* __restrict__ x, const unsigned short* __restrict__ Wt0,
    const float* __restrict__ br0, const float* __restrict__ dn_out,
    unsigned short* __restrict__ h0b, float* __restrict__ res0)
{
    __shared__ unsigned short xs[64][136];   // padded stride 272B
    int t = threadIdx.x;
    int lane = t & 63;
    int w = t >> 6;
    int g = lane >> 4, r16 = lane & 15;
    int rr = t >> 2, q4 = t & 3;

    bf16x8 bfrag[2][4];
    for (int i = 0; i < 2; ++i) {
        int n = (2 * w + i) * 16 + r16;
        for (int ks = 0; ks < 4; ++ks)
            bfrag[i][ks] = *(const bf16x8*)(Wt0 + n * 128 + ks * 32 + g * 8);
    }
    float br_c[2];
    for (int i = 0; i < 2; ++i) {
        int c = (2 * w + i) * 16 + r16;
        br_c[i] = (c >= 64) ? br0[c - 64] : 0.f;
    }

    for (int tile = blockIdx.x; tile < NTILE; tile += gridDim.x) {
        int row0 = tile * 64;
        {
            int R = row0 + rr;
            bool ok = (R < N_NODES);
            const float* xp = x + (size_t)R * IN_F + q4 * 32;
            for (int i = 0; i < 8; ++i) {
                float4 v = ok ? *(const float4*)(xp + i * 4) : make_float4(0.f, 0.f, 0.f, 0.f);
                unsigned p0 = (unsigned)f2b(v.x) | ((unsigned)f2b(v.y) << 16);
                unsigned p1 = (unsigned)f2b(v.z) | ((unsigned)f2b(v.w) << 16);
                *(uint2*)(&xs[rr][q4 * 32 + i * 4]) = make_uint2(p0, p1);
            }
        }
        __syncthreads();

        f32x4 acc[4][2];
        for (int rg16 = 0; rg16 < 4; ++rg16)
            for (int i = 0; i < 2; ++i)
                acc[rg16][i] = (f32x4){0.f, 0.f, 0.f, 0.f};

        for (int rg16 = 0; rg16 < 4; ++rg16) {
            int arow = rg16 * 16 + r16;
            bf16x8 a[4];
            for (int ks = 0; ks < 4; ++ks)
                a[ks] = *(const bf16x8*)(&xs[arow][ks * 32 + g * 8]);
            for (int ks = 0; ks < 4; ++ks)
                for (int i = 0; i < 2; ++i)
                    acc[rg16][i] = __builtin_amdgcn_mfma_f32_16x16x32_bf16(a[ks], bfrag[i][ks], acc[rg16][i], 0, 0, 0);
        }

        for (int rg16 = 0; rg16 < 4; ++rg16) {
            int Rbase = row0 + rg16 * 16 + g * 4;
            float dn[4];
            for (int rg = 0; rg < 4; ++rg) {
                int R = Rbase + rg;
                dn[rg] = (R < N_NODES) ? dn_out[R] : 0.f;
            }
            for (int i = 0; i < 2; ++i) {
                int c = (2 * w + i) * 16 + r16;
                for (int rg = 0; rg < 4; ++rg) {
                    int R = Rbase + rg;
                    if (R < N_NODES) {
                        if (c < 64) h0b[(size_t)R * 64 + c] = f2b(dn[rg] * acc[rg16][i][rg]);
                        else        res0[(size_t)R * 64 + (c - 64)] = gelu_exact(acc[rg16][i][rg] + br_c[i]);
                    }
                }
            }
        }
        __syncthreads();
    }
}

// ---------------- gather-aggregate over bf16 rows (proven 16-lane uint2 version) ----------------
// MODE 0: out[n][c] = gelu(acc*dn_in + b0[c]) + out[n][c]   (f32; res0 in out, in-place)
// MODE 1: outb[n][c] = bf16(acc*dn_in)                       (bf16 aggs for gemm1)
template <int MODE>
__global__ __launch_bounds__(256) void k_agg(
    const int* __restrict__ row_start, const int* __restrict__ csr_src,
    const unsigned short* __restrict__ hb, const float* __restrict__ dn_in,
    const float* __restrict__ b0, float* __restrict__ out,
    unsigned short* __restrict__ outb)
{
    int node = blockIdx.x * 4 + (threadIdx.x >> 6);
    int lane = threadIdx.x & 63;
    int sub = lane >> 4, q = lane & 15;
    int beg = row_start[node], end = row_start[node + 1];
    float a0 = 0.f, a1 = 0.f, a2 = 0.f, a3 = 0.f;
    for (int j = beg; j < end; j += 64) {
        int idx = j + lane;
        int eid = (idx < end) ? csr_src[idx] : 0;
        int cnt = end - j; if (cnt > 64) cnt = 64;
        for (int u = sub; u < cnt; u += 4) {
            int s = __shfl(eid, u);
            uint2 v = *(const uint2*)(hb + (size_t)s * 64 + q * 4);
            a0 += b2f((unsigned short)(v.x & 0xFFFFu));
            a1 += b2f((unsigned short)(v.x >> 16));
            a2 += b2f((unsigned short)(v.y & 0xFFFFu));
            a3 += b2f((unsigned short)(v.y >> 16));
        }
    }
    a0 += __shfl_xor(a0, 16); a0 += __shfl_xor(a0, 32);
    a1 += __shfl_xor(a1, 16); a1 += __shfl_xor(a1, 32);
    a2 += __shfl_xor(a2, 16); a2 += __shfl_xor(a2, 32);
    a3 += __shfl_xor(a3, 16); a3 += __shfl_xor(a3, 32);
    if (sub == 0) {
        float dn = dn_in[node];
        size_t o = (size_t)node * 64 + q * 4;
        if (MODE == 0) {
            float4 r = *(const float4*)(out + o);
            float4 wv;
            wv.x = gelu_exact(a0 * dn + b0[q * 4 + 0]) + r.x;
            wv.y = gelu_exact(a1 * dn + b0[q * 4 + 1]) + r.y;
            wv.z = gelu_exact(a2 * dn + b0[q * 4 + 2]) + r.z;
            wv.w = gelu_exact(a3 * dn + b0[q * 4 + 3]) + r.w;
            *(float4*)(out + o) = wv;
        } else {
            unsigned p0 = (unsigned)f2b(a0 * dn) | ((unsigned)f2b(a1 * dn) << 16);
            unsigned p1 = (unsigned)f2b(a2 * dn) | ((unsigned)f2b(a3 * dn) << 16);
            *(uint2*)(outb + o) = make_uint2(p0, p1);
        }
    }
}

// ---------------- BN stats (layer 0 partials, float4 loads) ----------------
__global__ __launch_bounds__(256) void k_stats_partial(const float* __restrict__ x,
        double* __restrict__ psum, double* __restrict__ psumsq)
{
    __shared__ double ls[16][64], ls2[16][64];
    int t = threadIdx.x;
    int cq = t & 15;          // column quad: cols cq*4 .. cq*4+3
    int rq = t >> 4;          // 16 row groups
    int per = (N_NODES + SB - 1) / SB;
    int r0 = blockIdx.x * per;
    int r1 = r0 + per; if (r1 > N_NODES) r1 = N_NODES;
    double s0 = 0.0, s1 = 0.0, s2v = 0.0, s3 = 0.0;
    double q0 = 0.0, q1 = 0.0, q2 = 0.0, q3 = 0.0;
    for (int r = r0 + rq; r < r1; r += 16) {
        float4 v = *(const float4*)(x + (size_t)r * 64 + cq * 4);
        s0 += v.x; q0 += (double)v.x * v.x;
        s1 += v.y; q1 += (double)v.y * v.y;
        s2v += v.z; q2 += (double)v.z * v.z;
        s3 += v.w; q3 += (double)v.w * v.w;
    }
    ls[rq][cq * 4 + 0] = s0;  ls2[rq][cq * 4 + 0] = q0;
    ls[rq][cq * 4 + 1] = s1;  ls2[rq][cq * 4 + 1] = q1;
    ls[rq][cq * 4 + 2] = s2v; ls2[rq][cq * 4 + 2] = q2;
    ls[rq][cq * 4 + 3] = s3;  ls2[rq][cq * 4 + 3] = q3;
    __syncthreads();
    if (t < 64) {
        double a = 0.0, a2 = 0.0;
        for (int i = 0; i < 16; ++i) { a += ls[i][t]; a2 += ls2[i][t]; }
        psum[blockIdx.x * 64 + t] = a;
        psumsq[blockIdx.x * 64 + t] = a2;
    }
}

// ---------------- two-stage column reduce: 64 blocks, one per column ----------------
template <typename T, int NB>
__global__ __launch_bounds__(256) void k_colred(const T* __restrict__ ps, const T* __restrict__ ps2,
                                                double* __restrict__ ds, double* __restrict__ ds2) {
    __shared__ double l1[256], l2[256];
    int c = blockIdx.x;  // 0..63
    int t = threadIdx.x;
    double s = 0.0, s2 = 0.0;
    for (int b = t; b < NB; b += 256) {
        s += (double)ps[(size_t)b * 64 + c];
        s2 += (double)ps2[(size_t)b * 64 + c];
    }
    l1[t] = s; l2[t] = s2;
    __syncthreads();
    for (int d = 128; d > 0; d >>= 1) {
        if (t < d) { l1[t] += l1[t + d]; l2[t] += l2[t + d]; }
        __syncthreads();
    }
    if (t == 0) { ds[c] = l1[0]; ds2[c] = l2[0]; }
}

__global__ void k_bn_final(const double* __restrict__ ds, const double* __restrict__ ds2,
                           const float* __restrict__ g, const float* __restrict__ be,
                           float* __restrict__ scale, float* __restrict__ shift) {
    int c = threadIdx.x;
    if (c < 64) {
        double mean = ds[c] / N_NODES;
        double var = ds2[c] / N_NODES - mean * mean;
        float inv = (float)(1.0 / sqrt(var + (double)EPS)) * g[c];
        scale[c] = inv;
        shift[c] = be[c] - (float)mean * inv;
    }
}

// ---------------- h1b = bf16((scale*new0+shift)*dn_out) (4 elems/thread) ----------------
__global__ __launch_bounds__(256) void k_norm1(const float* __restrict__ scale,
                        const float* __restrict__ shift,
                        const float* __restrict__ dn_out,
                        const float* __restrict__ new0, unsigned short* __restrict__ h1b)
{
    int idx = blockIdx.x * 256 + threadIdx.x;   // one per 4 elements
    int r = idx >> 4, q = idx & 15;
    float dn = dn_out[r];
    float4 v = *(const float4*)(new0 + (size_t)r * 64 + q * 4);
    float4 sc = *(const float4*)(scale + q * 4);
    float4 sh = *(const float4*)(shift + q * 4);
    unsigned short h0 = f2b((sc.x * v.x + sh.x) * dn);
    unsigned short h1 = f2b((sc.y * v.y + sh.y) * dn);
    unsigned short h2 = f2b((sc.z * v.z + sh.z) * dn);
    unsigned short h3 = f2b((sc.w * v.w + sh.w) * dn);
    unsigned p0 = (unsigned)h0 | ((unsigned)h1 << 16);
    unsigned p1 = (unsigned)h2 | ((unsigned)h3 << 16);
    *(uint2*)(h1b + (size_t)r * 64 + q * 4) = make_uint2(p0, p1);
}

// ---------------- layer1 MFMA GEMM (column-split waves, grid = NTILE, fused BN stats) ----------------
// out = gelu(aggb@W1+b1) + gelu((scale0*new0+shift0)@Wr1+br1); aggb is bf16.
// wave w owns output cols w*16..w*16+15 (both W and R paths), all 64 rows.
__global__ __launch_bounds__(256) void k_gemm1(
    const unsigned short* __restrict__ aggb, const float* __restrict__ new0,
    const unsigned short* __restrict__ Wt1,
    const float* __restrict__ b1_, const float* __restrict__ br1,
    const float* __restrict__ scale0, const float* __restrict__ shift0,
    float* __restrict__ out_new,
    float* __restrict__ psum1, float* __restrict__ psumsq1)
{
    __shared__ unsigned short xa[64][72];   // stride 144B = 9 x 16B
    __shared__ unsigned short xb[64][72];
    __shared__ float cs[64], cs2[64];
    int t = threadIdx.x;
    int lane = t & 63;
    int w = t >> 6;
    int g = lane >> 4, r16 = lane & 15;
    int rr = t >> 2, q4 = t & 3;

    bf16x8 bW[2], bR[2];
    {
        int n = w * 16 + r16;
        for (int ks = 0; ks < 2; ++ks) {
            bW[ks] = *(const bf16x8*)(Wt1 + n * 64 + ks * 32 + g * 8);
            bR[ks] = *(const bf16x8*)(Wt1 + (64 + n) * 64 + ks * 32 + g * 8);
        }
    }
    float bias1 = b1_[w * 16 + r16];
    float biasr = br1[w * 16 + r16];
    float4 sc_[4], sh_[4];
    for (int i = 0; i < 4; ++i) {
        sc_[i] = *(const float4*)(scale0 + q4 * 16 + i * 4);
        sh_[i] = *(const float4*)(shift0 + q4 * 16 + i * 4);
    }
    float s_ = 0.f, s2_ = 0.f;

    if (t < 64) { cs[t] = 0.f; cs2[t] = 0.f; }

    for (int tile = blockIdx.x; tile < NTILE; tile += gridDim.x) {
        int row0 = tile * 64;
        {
            int R = row0 + rr;
            bool ok = (R < N_NODES);
            const unsigned short* pa = aggb + (size_t)R * 64 + q4 * 16;
            const float* pb = new0 + (size_t)R * 64 + q4 * 16;
            for (int i = 0; i < 4; ++i) {
                uint2 va = ok ? *(const uint2*)(pa + i * 4) : make_uint2(0u, 0u);
                float4 vb = ok ? *(const float4*)(pb + i * 4) : make_float4(0.f, 0.f, 0.f, 0.f);
                vb.x = sc_[i].x * vb.x + sh_[i].x;
                vb.y = sc_[i].y * vb.y + sh_[i].y;
                vb.z = sc_[i].z * vb.z + sh_[i].z;
                vb.w = sc_[i].w * vb.w + sh_[i].w;
                unsigned pb0 = (unsigned)f2b(vb.x) | ((unsigned)f2b(vb.y) << 16);
                unsigned pb1 = (unsigned)f2b(vb.z) | ((unsigned)f2b(vb.w) << 16);
                *(uint2*)(&xa[rr][q4 * 16 + i * 4]) = va;
                *(uint2*)(&xb[rr][q4 * 16 + i * 4]) = make_uint2(pb0, pb1);
            }
        }
        __syncthreads();

        int c = w * 16 + r16;
        for (int rg16 = 0; rg16 < 4; ++rg16) {
            int arow = rg16 * 16 + r16;
            bf16x8 aA[2], aB[2];
            for (int ks = 0; ks < 2; ++ks) {
                aA[ks] = *(const bf16x8*)(&xa[arow][ks * 32 + g * 8]);
                aB[ks] = *(const bf16x8*)(&xb[arow][ks * 32 + g * 8]);
            }
            f32x4 accW = (f32x4){0.f, 0.f, 0.f, 0.f};
            f32x4 accR = (f32x4){0.f, 0.f, 0.f, 0.f};
            for (int ks = 0; ks < 2; ++ks) {
                accW = __builtin_amdgcn_mfma_f32_16x16x32_bf16(aA[ks], bW[ks], accW, 0, 0, 0);
                accR = __builtin_amdgcn_mfma_f32_16x16x32_bf16(aB[ks], bR[ks], accR, 0, 0, 0);
            }
            int Rbase = row0 + rg16 * 16 + g * 4;
            for (int rg = 0; rg < 4; ++rg) {
                int R = Rbase + rg;
                if (R < N_NODES) {
                    float v = gelu_exact(accW[rg] + bias1) + gelu_exact(accR[rg] + biasr);
                    out_new[(size_t)R * 64 + c] = v;
                    s_ += v;
                    s2_ += v * v;
                }
            }
        }
        __syncthreads();
    }

    // fused BN-stats partial reduce (cs was zeroed before first barrier)
    atomicAdd(&cs[w * 16 + r16], s_);
    atomicAdd(&cs2[w * 16 + r16], s2_);
    __syncthreads();
    if (t < 64) {
        psum1[blockIdx.x * 64 + t] = cs[t];
        psumsq1[blockIdx.x * 64 + t] = cs2[t];
    }
}

// ---------------- head ----------------
__global__ void k_final(const int* __restrict__ offsets,
                        const float* __restrict__ h2,
                        const float* __restrict__ scale, const float* __restrict__ shift,
                        const float* __restrict__ Wl, const float* __restrict__ bl,
                        float* __restrict__ out)
{
    __shared__ float xv[64];
    int g = blockIdx.x;
    int t = threadIdx.x;
    int row = offsets[g];
    if (t < 64) xv[t] = h2[(size_t)row * 64 + t] * scale[t] + shift[t];
    __syncthreads();
    if (t < N_CLS) {
        float s = bl[t];
        for (int k = 0; k < 64; ++k) s += xv[k] * Wl[k * N_CLS + t];
        out[g * N_CLS + t] = s;
    }
}

extern "C" void kernel_launch(void* const* d_in, const int* in_sizes, int n_in,
                              void* d_out, int out_size, void* d_ws, size_t ws_size,
                              hipStream_t stream)
{
    const float* feats = (const float*)d_in[0];
    const int* src     = (const int*)d_in[1];
    const int* dst     = (const int*)d_in[2];
    const int* offsets = (const int*)d_in[3];
    const float* W0  = (const float*)d_in[4];
    const float* b0  = (const float*)d_in[5];
    const float* Wr0 = (const float*)d_in[6];
    const float* br0 = (const float*)d_in[7];
    const float* g0  = (const float*)d_in[8];
    const float* be0 = (const float*)d_in[9];
    const float* W1  = (const float*)d_in[10];
    const float* b1  = (const float*)d_in[11];
    const float* Wr1 = (const float*)d_in[12];
    const float* br1 = (const float*)d_in[13];
    const float* g1  = (const float*)d_in[14];
    const float* be1 = (const float*)d_in[15];
    const float* Wl  = (const float*)d_in[16];
    const float* bl  = (const float*)d_in[17];
    float* out = (float*)d_out;

    char* ws = (char*)d_ws;
    size_t off = 0;
    auto alloc = [&](size_t bytes) -> void* {
        off = (off + 255) & ~(size_t)255;
        void* p = ws + off;
        off += bytes;
        return p;
    };

    const size_t NB = (size_t)N_NODES * HID * sizeof(float);  // 25.6MB
    unsigned short* Hb = (unsigned short*)alloc(NB / 2);  // h0b / h1b (bf16)
    float* B = (float*)alloc(NB);                         // res0 -> new0
    float* C = (float*)alloc(NB);                         // hist partials (early) / new1
    unsigned* P = (unsigned*)C;                           // 16.8MB alias, dead before k_gemm1
    unsigned short* Ab = (unsigned short*)alloc(NB / 2);  // bf16 aggs (layer1): N_NODES*64*2B = 12.8MB
    unsigned short* Wt0 = (unsigned short*)alloc(128 * 128 * sizeof(unsigned short));
    unsigned short* Wt1 = (unsigned short*)alloc(128 * 64 * sizeof(unsigned short));
    int* cnt_in = (int*)alloc((size_t)N_NODES * sizeof(int));
    float* dn_out = (float*)alloc(N_NODES * sizeof(float));
    float* dn_in  = (float*)alloc(N_NODES * sizeof(float));
    int* bsum = (int*)alloc(SCAN_BLK * sizeof(int));
    int* bpre = (int*)alloc(SCAN_BLK * sizeof(int));
    int* row_start = (int*)alloc((SCAN_BLK * 256 + 1) * sizeof(int));
    int* csr_src   = (int*)alloc((size_t)N_EDGES * sizeof(int));
    double* psum   = (double*)alloc((size_t)SB * 64 * sizeof(double));
    double* psumsq = (double*)alloc((size_t)SB * 64 * sizeof(double));
    float* psum1   = (float*)alloc((size_t)NTILE * 64 * sizeof(float));
    float* psumsq1 = (float*)alloc((size_t)NTILE * 64 * sizeof(float));
    double* dsum   = (double*)alloc(64 * sizeof(double));
    double* dsumsq = (double*)alloc(64 * sizeof(double));
    float* scale0 = (float*)alloc(64 * sizeof(float));
    float* shift0 = (float*)alloc(64 * sizeof(float));
    float* scale1 = (float*)alloc(64 * sizeof(float));
    float* shift1 = (float*)alloc(64 * sizeof(float));
    (void)ws_size; (void)n_in; (void)in_sizes; (void)out_size;

    // weight prep + degree histograms + CSR (reused by both layers)
    k_prep_w<<<64, 256, 0, stream>>>(W0, Wr0, W1, Wr1, Wt0, Wt1);
    k_hist<<<2 * HNR * HNC, 256, 0, stream>>>(src, dst, P);
    k_hist_reduce<<<HNR * HWORDS / 256, 256, 0, stream>>>(P, cnt_in, dn_in, dn_out);
    k_scan_reduce<<<SCAN_BLK, 256, 0, stream>>>(cnt_in, bsum);
    k_scan_bsum<<<1, 512, 0, stream>>>(bsum, bpre);
    k_scan_write<<<SCAN_BLK, 256, 0, stream>>>(cnt_in, bpre, row_start);
    k_fill2<<<FNR * HNC, 256, 0, stream>>>(src, dst, row_start, P, csr_src);

    // layer 0
    k_gemm0<<<NTILE, 256, 0, stream>>>(feats, Wt0, br0, dn_out, Hb, B);
    k_agg<0><<<N_NODES / 4, 256, 0, stream>>>(row_start, csr_src, Hb, dn_in, b0, B, nullptr);
    k_stats_partial<<<SB, 256, 0, stream>>>(B, psum, psumsq);
    k_colred<double, SB><<<64, 256, 0, stream>>>(psum, psumsq, dsum, dsumsq);
    k_bn_final<<<1, 64, 0, stream>>>(dsum, dsumsq, g0, be0, scale0, shift0);
    k_norm1<<<(N_NODES * HID / 4) / 256, 256, 0, stream>>>(scale0, shift0, dn_out, B, Hb);

    // layer 1
    k_agg<1><<<N_NODES / 4, 256, 0, stream>>>(row_start, csr_src, Hb, dn_in, nullptr, nullptr, Ab);
    k_gemm1<<<NTILE, 256, 0, stream>>>(Ab, B, Wt1, b1, br1, scale0, shift0, C, psum1, psumsq1);
    k_colred<float, NTILE><<<64, 256, 0, stream>>>(psum1, psumsq1, dsum, dsumsq);
    k_bn_final<<<1, 64, 0, stream>>>(dsum, dsumsq, g1, be1, scale1, shift1);

    // head
    k_final<<<N_GRAPHS, 64, 0, stream>>>(offsets, C, scale1, shift1, Wl, bl, out);
}

// Round 18
// 264.232 us; speedup vs baseline: 1.2924x; 1.0024x over previous
//
#include <hip/hip_runtime.h>
#include <hip/hip_bf16.h>
#include <math.h>

#define N_NODES 100000
#define N_EDGES 1000000
#define N_GRAPHS 100
#define IN_F 128
#define HID 64
#define N_CLS 40
#define EPS 1e-5f
#define SB 512          // stats partial blocks (layer0)
#define SCAN_BLK 391    // 391*256 = 100096 >= N_NODES+1
#define NTILE 1563      // ceil(N_NODES/64); gemm grids + gemm1 stats partial count

// histogram geometry
#define HRANGE 32768            // nodes per range (2 per u32 word)
#define HNR 4                   // ranges: 4*32768 >= N_NODES
#define HNC 32                  // edge chunks
#define HWORDS (HRANGE / 2)     // 16384 u32 words = 64KB LDS
#define HESLICE (N_EDGES / HNC) // 31250

// fill geometry (sub-ranges of 4096 nodes; 24KB LDS)
#define FRANGE 4096
#define FNR 25                  // 25*4096 = 102400 >= N_NODES

typedef __attribute__((ext_vector_type(8))) short bf16x8;
typedef __attribute__((ext_vector_type(4))) float f32x4;

__device__ __forceinline__ float gelu_exact(float x) {
    return 0.5f * x * (1.0f + erff(x * 0.70710678118654752f));
}

__device__ __forceinline__ unsigned short f2b(float f) {  // f32 -> bf16 RNE
    unsigned u = __builtin_bit_cast(unsigned, f);
    return (unsigned short)((u + 0x7FFFu + ((u >> 16) & 1u)) >> 16);
}
__device__ __forceinline__ float b2f(unsigned short h) {
    unsigned u = ((unsigned)h) << 16;
    return __builtin_bit_cast(float, u);
}

// ---------------- weight prep: Wt0[n][k] bf16 (n<64:W0, else Wr0), Wt1 likewise
__global__ void k_prep_w(const float* __restrict__ W0, const float* __restrict__ Wr0,
                         const float* __restrict__ W1, const float* __restrict__ Wr1,
                         unsigned short* __restrict__ Wt0, unsigned short* __restrict__ Wt1) {
    int t = blockIdx.x * 256 + threadIdx.x;
    for (int idx = t; idx < 128 * 128; idx += gridDim.x * 256) {
        int n = idx >> 7, k = idx & 127;
        float v = (n < 64) ? W0[k * 64 + n] : Wr0[k * 64 + (n - 64)];
        Wt0[n * 128 + k] = f2b(v);
    }
    for (int idx = t; idx < 128 * 64; idx += gridDim.x * 256) {
        int n = idx >> 6, k = idx & 63;
        float v = (n < 64) ? W1[k * 64 + n] : Wr1[k * 64 + (n - 64)];
        Wt1[n * 64 + k] = f2b(v);
    }
}

// ---------------- LDS-privatized degree histogram (no global atomics) ----------------
__global__ __launch_bounds__(256) void k_hist(const int* __restrict__ src,
                                              const int* __restrict__ dst,
                                              unsigned* __restrict__ P) {
    __shared__ unsigned h[HWORDS];
    int t = threadIdx.x;
    int b = blockIdx.x;
    int chunk = b & (HNC - 1);
    int job = b >> 5;
    int range = job & (HNR - 1);
    const int* v = (job < HNR) ? dst : src;
    int base = range * HRANGE;
    for (int i = t; i < HWORDS; i += 256) h[i] = 0;
    __syncthreads();
    int e0 = chunk * HESLICE;
    for (int i = t; i < HESLICE / 2; i += 256) {
        uint2 d2 = *(const uint2*)(v + e0 + 2 * i);
        int o = (int)d2.x - base;
        if ((unsigned)o < HRANGE) atomicAdd(&h[o >> 1], 1u << ((o & 1) * 16));
        o = (int)d2.y - base;
        if ((unsigned)o < HRANGE) atomicAdd(&h[o >> 1], 1u << ((o & 1) * 16));
    }
    __syncthreads();
    unsigned* outp = P + (size_t)b * HWORDS;
    for (int i = t; i < HWORDS; i += 256) outp[i] = h[i];
}

// sum partials -> cnt_in, dn_in, dn_out; ALSO rewrite dst-partials in place as
// exclusive chunk-prefix (packed u16 add is carry-safe: per-node totals << 65536).
__global__ __launch_bounds__(256) void k_hist_reduce(unsigned* __restrict__ P,
                                                     int* __restrict__ cnt_in,
                                                     float* __restrict__ dn_in,
                                                     float* __restrict__ dn_out) {
    int w = blockIdx.x * 256 + threadIdx.x;   // 0 .. HNR*HWORDS-1 (65536)
    int range = w >> 14;
    int widx = w & (HWORDS - 1);
    unsigned* pin  = P + (size_t)(range * HNC) * HWORDS + widx;
    const unsigned* pout = P + (size_t)((HNR + range) * HNC) * HWORDS + widx;
    unsigned s_in = 0, s_out = 0;
    for (int c = 0; c < HNC; ++c) {
        unsigned v = pin[(size_t)c * HWORDS];
        pin[(size_t)c * HWORDS] = s_in;      // exclusive prefix along chunk axis
        s_in += v;
        s_out += pout[(size_t)c * HWORDS];
    }
    int n0 = range * HRANGE + widx * 2;
    unsigned ci0 = s_in & 0xFFFFu,  ci1 = s_in >> 16;
    unsigned co0 = s_out & 0xFFFFu, co1 = s_out >> 16;
    if (n0 < N_NODES) {
        cnt_in[n0] = (int)ci0;
        dn_in[n0]  = rsqrtf((float)(ci0 > 0 ? ci0 : 1));
        dn_out[n0] = rsqrtf((float)(co0 > 0 ? co0 : 1));
    }
    if (n0 + 1 < N_NODES) {
        cnt_in[n0 + 1] = (int)ci1;
        dn_in[n0 + 1]  = rsqrtf((float)(ci1 > 0 ? ci1 : 1));
        dn_out[n0 + 1] = rsqrtf((float)(co1 > 0 ? co1 : 1));
    }
}

// ---------------- CSR build ----------------
__global__ __launch_bounds__(256) void k_scan_reduce(const int* __restrict__ cnt,
                                                     int* __restrict__ bsum) {
    __shared__ int sh[256];
    int t = threadIdx.x;
    int i = blockIdx.x * 256 + t;
    int c = (i < N_NODES) ? cnt[i] : 0;
    sh[t] = c;
    __syncthreads();
    for (int d = 128; d > 0; d >>= 1) {
        if (t < d) sh[t] += sh[t + d];
        __syncthreads();
    }
    if (t == 0) bsum[blockIdx.x] = sh[0];
}

__global__ __launch_bounds__(512) void k_scan_bsum(const int* __restrict__ bsum,
                                                   int* __restrict__ bpre) {
    __shared__ int sh[512];
    int t = threadIdx.x;
    int v = (t < SCAN_BLK) ? bsum[t] : 0;
    sh[t] = v;
    __syncthreads();
    for (int d = 1; d < 512; d <<= 1) {
        int x = (t >= d) ? sh[t - d] : 0;
        __syncthreads();
        sh[t] += x;
        __syncthreads();
    }
    if (t < SCAN_BLK) bpre[t] = sh[t] - v;
}

__global__ __launch_bounds__(256) void k_scan_write(const int* __restrict__ cnt_in,
                                                    const int* __restrict__ bpre,
                                                    int* __restrict__ row_start) {
    __shared__ int sh[256];
    int t = threadIdx.x;
    int i = blockIdx.x * 256 + t;
    int c = (i < N_NODES) ? cnt_in[i] : 0;
    sh[t] = c;
    __syncthreads();
    for (int d = 1; d < 256; d <<= 1) {
        int v = (t >= d) ? sh[t - d] : 0;
        __syncthreads();
        sh[t] += v;
        __syncthreads();
    }
    int excl = sh[t] - c + bpre[blockIdx.x];
    if (i <= N_NODES) row_start[i] = excl;
}

// ---------------- atomic-free CSR fill (uint2 edge loads, unconditional) ----------------
__global__ __launch_bounds__(256) void k_fill2(const int* __restrict__ src,
                                               const int* __restrict__ dst,
                                               const int* __restrict__ row_start,
                                               const unsigned* __restrict__ Ppre,
                                               int* __restrict__ csr_src) {
    __shared__ unsigned base[FRANGE];       // 16 KB
    __shared__ unsigned curs[FRANGE / 2];   // 8 KB (packed u16 pairs)
    int t = threadIdx.x;
    int b = blockIdx.x;
    int c = b & (HNC - 1);
    int fr = b >> 5;
    int r = fr >> 3;                        // hist range (32768 nodes)
    int sub = fr & 7;                       // eighth within hist range
    int n0 = fr * FRANGE;
    const unsigned* pp = Ppre + (size_t)(r * HNC + c) * HWORDS + sub * (FRANGE / 2);
    for (int i = t; i < FRANGE / 2; i += 256) {
        unsigned pref = pp[i];
        int n = n0 + 2 * i;
        int2 rs = *(const int2*)(row_start + n);  // overread past N_NODES stays in ws; guarded
        base[2 * i]     = (n < N_NODES)     ? (unsigned)rs.x + (pref & 0xFFFFu) : 0u;
        base[2 * i + 1] = (n + 1 < N_NODES) ? (unsigned)rs.y + (pref >> 16)     : 0u;
        curs[i] = 0;
    }
    __syncthreads();
    int e0 = c * HESLICE;
    for (int i = t; i < HESLICE / 2; i += 256) {
        uint2 d2 = *(const uint2*)(dst + e0 + 2 * i);
        uint2 s2 = *(const uint2*)(src + e0 + 2 * i);
        int o0 = (int)d2.x - n0;
        if ((unsigned)o0 < FRANGE) {
            unsigned old = atomicAdd(&curs[o0 >> 1], 1u << ((o0 & 1) * 16));
            unsigned loc = (old >> ((o0 & 1) * 16)) & 0xFFFFu;
            csr_src[base[o0] + loc] = (int)s2.x;
        }
        int o1 = (int)d2.y - n0;
        if ((unsigned)o1 < FRANGE) {
            unsigned old = atomicAdd(&curs[o1 >> 1], 1u << ((o1 & 1) * 16));
            unsigned loc = (old >> ((o1 & 1) * 16)) & 0xFFFFu;
            csr_src[base[o1] + loc] = (int)s2.y;
        }
    }
}

// ---------------- layer0 MFMA GEMM (column-split waves, grid = NTILE) ----------------
// h0b = bf16(dn_out*(x@W0)), res0 = gelu(x@Wr0+br0)
// wave w owns cols w*32..w*32+31 (2 col-tiles), all 64 rows. bfrag = 32 VGPRs.
__global__ __launch_bounds__(256) void k_gemm0(
    const float* __restrict__ x, const unsigned short* __restrict__ Wt0,
    const float* __restrict__ br0, const float* __restrict__ dn_out,
    unsigned short* __restrict__ h0b, float* __restrict__ res0)
{
    __shared__ unsigned short xs[64][136];   // padded stride 272B
    int t = threadIdx.x;
    int lane = t & 63;
    int w = t >> 6;
    int g = lane >> 4, r16 = lane & 15;
    int rr = t >> 2, q4 = t & 3;

    bf16x8 bfrag[2][4];
    for (int i = 0; i < 2; ++i) {
        int n = (2 * w + i) * 16 + r16;
        for (int ks = 0; ks < 4; ++ks)
            bfrag[i][ks] = *(const bf16x8*)(Wt0 + n * 128 + ks * 32 + g * 8);
    }
    float br_c[2];
    for (int i = 0; i < 2; ++i) {
        int c = (2 * w + i) * 16 + r16;
        br_c[i] = (c >= 64) ? br0[c - 64] : 0.f;
    }

    for (int tile = blockIdx.x; tile < NTILE; tile += gridDim.x) {
        int row0 = tile * 64;
        {
            int R = row0 + rr;
            bool ok = (R < N_NODES);
            const float* xp = x + (size_t)R * IN_F + q4 * 32;
            for (int i = 0; i < 8; ++i) {
                float4 v = ok ? *(const float4*)(xp + i * 4) : make_float4(0.f, 0.f, 0.f, 0.f);
                unsigned p0 = (unsigned)f2b(v.x) | ((unsigned)f2b(v.y) << 16);
                unsigned p1 = (unsigned)f2b(v.z) | ((unsigned)f2b(v.w) << 16);
                *(uint2*)(&xs[rr][q4 * 32 + i * 4]) = make_uint2(p0, p1);
            }
        }
        __syncthreads();

        f32x4 acc[4][2];
        for (int rg16 = 0; rg16 < 4; ++rg16)
            for (int i = 0; i < 2; ++i)
                acc[rg16][i] = (f32x4){0.f, 0.f, 0.f, 0.f};

        for (int rg16 = 0; rg16 < 4; ++rg16) {
            int arow = rg16 * 16 + r16;
            bf16x8 a[4];
            for (int ks = 0; ks < 4; ++ks)
                a[ks] = *(const bf16x8*)(&xs[arow][ks * 32 + g * 8]);
            for (int ks = 0; ks < 4; ++ks)
                for (int i = 0; i < 2; ++i)
                    acc[rg16][i] = __builtin_amdgcn_mfma_f32_16x16x32_bf16(a[ks], bfrag[i][ks], acc[rg16][i], 0, 0, 0);
        }

        for (int rg16 = 0; rg16 < 4; ++rg16) {
            int Rbase = row0 + rg16 * 16 + g * 4;
            float dn[4];
            for (int rg = 0; rg < 4; ++rg) {
                int R = Rbase + rg;
                dn[rg] = (R < N_NODES) ? dn_out[R] : 0.f;
            }
            for (int i = 0; i < 2; ++i) {
                int c = (2 * w + i) * 16 + r16;
                for (int rg = 0; rg < 4; ++rg) {
                    int R = Rbase + rg;
                    if (R < N_NODES) {
                        if (c < 64) h0b[(size_t)R * 64 + c] = f2b(dn[rg] * acc[rg16][i][rg]);
                        else        res0[(size_t)R * 64 + (c - 64)] = gelu_exact(acc[rg16][i][rg] + br_c[i]);
                    }
                }
            }
        }
        __syncthreads();
    }
}

// ---------------- gather-aggregate over bf16 rows ----------------
// Proven 16-lane uint2 mapping; software-pipelined row loads (2 in flight).
// Accumulation set and ORDER identical to the proven version -> bitwise-identical sums.
// MODE 0: out[n][c] = gelu(acc*dn_in + b0[c]) + out[n][c]   (f32; res0 in out, in-place)
// MODE 1: outb[n][c] = bf16(acc*dn_in)                       (bf16 aggs for gemm1)
template <int MODE>
__global__ __launch_bounds__(256) void k_agg(
    const int* __restrict__ row_start, const int* __restrict__ csr_src,
    const unsigned short* __restrict__ hb, const float* __restrict__ dn_in,
    const float* __restrict__ b0, float* __restrict__ out,
    unsigned short* __restrict__ outb)
{
    int node = blockIdx.x * 4 + (threadIdx.x >> 6);
    int lane = threadIdx.x & 63;
    int sub = lane >> 4, q = lane & 15;
    int beg = row_start[node], end = row_start[node + 1];
    float a0 = 0.f, a1 = 0.f, a2 = 0.f, a3 = 0.f;
    for (int j = beg; j < end; j += 64) {
        int idx = j + lane;
        int eid = (idx < end) ? csr_src[idx] : 0;
        int cnt = end - j; if (cnt > 64) cnt = 64;
        int u = sub;
        uint2 vnext = make_uint2(0u, 0u);
        if (u < cnt) {
            int s = __shfl(eid, u);
            vnext = *(const uint2*)(hb + (size_t)s * 64 + q * 4);
        }
        for (; u < cnt; u += 4) {
            uint2 v = vnext;
            int u2 = u + 4;
            if (u2 < cnt) {
                int s2 = __shfl(eid, u2);
                vnext = *(const uint2*)(hb + (size_t)s2 * 64 + q * 4);
            }
            a0 += b2f((unsigned short)(v.x & 0xFFFFu));
            a1 += b2f((unsigned short)(v.x >> 16));
            a2 += b2f((unsigned short)(v.y & 0xFFFFu));
            a3 += b2f((unsigned short)(v.y >> 16));
        }
    }
    a0 += __shfl_xor(a0, 16); a0 += __shfl_xor(a0, 32);
    a1 += __shfl_xor(a1, 16); a1 += __shfl_xor(a1, 32);
    a2 += __shfl_xor(a2, 16); a2 += __shfl_xor(a2, 32);
    a3 += __shfl_xor(a3, 16); a3 += __shfl_xor(a3, 32);
    if (sub == 0) {
        float dn = dn_in[node];
        size_t o = (size_t)node * 64 + q * 4;
        if (MODE == 0) {
            float4 r = *(const float4*)(out + o);
            float4 wv;
            wv.x = gelu_exact(a0 * dn + b0[q * 4 + 0]) + r.x;
            wv.y = gelu_exact(a1 * dn + b0[q * 4 + 1]) + r.y;
            wv.z = gelu_exact(a2 * dn + b0[q * 4 + 2]) + r.z;
            wv.w = gelu_exact(a3 * dn + b0[q * 4 + 3]) + r.w;
            *(float4*)(out + o) = wv;
        } else {
            unsigned p0 = (unsigned)f2b(a0 * dn) | ((unsigned)f2b(a1 * dn) << 16);
            unsigned p1 = (unsigned)f2b(a2 * dn) | ((unsigned)f2b(a3 * dn) << 16);
            *(uint2*)(outb + o) = make_uint2(p0, p1);
        }
    }
}

// ---------------- BN stats (layer 0 partials, float4 loads) ----------------
__global__ __launch_bounds__(256) void k_stats_partial(const float* __restrict__ x,
        double* __restrict__ psum, double* __restrict__ psumsq)
{
    __shared__ double ls[16][64], ls2[16][64];
    int t = threadIdx.x;
    int cq = t & 15;          // column quad: cols cq*4 .. cq*4+3
    int rq = t >> 4;          // 16 row groups
    int per = (N_NODES + SB - 1) / SB;
    int r0 = blockIdx.x * per;
    int r1 = r0 + per; if (r1 > N_NODES) r1 = N_NODES;
    double s0 = 0.0, s1 = 0.0, s2v = 0.0, s3 = 0.0;
    double q0 = 0.0, q1 = 0.0, q2 = 0.0, q3 = 0.0;
    for (int r = r0 + rq; r < r1; r += 16) {
        float4 v = *(const float4*)(x + (size_t)r * 64 + cq * 4);
        s0 += v.x; q0 += (double)v.x * v.x;
        s1 += v.y; q1 += (double)v.y * v.y;
        s2v += v.z; q2 += (double)v.z * v.z;
        s3 += v.w; q3 += (double)v.w * v.w;
    }
    ls[rq][cq * 4 + 0] = s0;  ls2[rq][cq * 4 + 0] = q0;
    ls[rq][cq * 4 + 1] = s1;  ls2[rq][cq * 4 + 1] = q1;
    ls[rq][cq * 4 + 2] = s2v; ls2[rq][cq * 4 + 2] = q2;
    ls[rq][cq * 4 + 3] = s3;  ls2[rq][cq * 4 + 3] = q3;
    __syncthreads();
    if (t < 64) {
        double a = 0.0, a2 = 0.0;
        for (int i = 0; i < 16; ++i) { a += ls[i][t]; a2 += ls2[i][t]; }
        psum[blockIdx.x * 64 + t] = a;
        psumsq[blockIdx.x * 64 + t] = a2;
    }
}

// ---------------- two-stage column reduce: 64 blocks, one per column ----------------
template <typename T, int NB>
__global__ __launch_bounds__(256) void k_colred(const T* __restrict__ ps, const T* __restrict__ ps2,
                                                double* __restrict__ ds, double* __restrict__ ds2) {
    __shared__ double l1[256], l2[256];
    int c = blockIdx.x;  // 0..63
    int t = threadIdx.x;
    double s = 0.0, s2 = 0.0;
    for (int b = t; b < NB; b += 256) {
        s += (double)ps[(size_t)b * 64 + c];
        s2 += (double)ps2[(size_t)b * 64 + c];
    }
    l1[t] = s; l2[t] = s2;
    __syncthreads();
    for (int d = 128; d > 0; d >>= 1) {
        if (t < d) { l1[t] += l1[t + d]; l2[t] += l2[t + d]; }
        __syncthreads();
    }
    if (t == 0) { ds[c] = l1[0]; ds2[c] = l2[0]; }
}

__global__ void k_bn_final(const double* __restrict__ ds, const double* __restrict__ ds2,
                           const float* __restrict__ g, const float* __restrict__ be,
                           float* __restrict__ scale, float* __restrict__ shift) {
    int c = threadIdx.x;
    if (c < 64) {
        double mean = ds[c] / N_NODES;
        double var = ds2[c] / N_NODES - mean * mean;
        float inv = (float)(1.0 / sqrt(var + (double)EPS)) * g[c];
        scale[c] = inv;
        shift[c] = be[c] - (float)mean * inv;
    }
}

// ---------------- h1b = bf16((scale*new0+shift)*dn_out) (4 elems/thread) ----------------
__global__ __launch_bounds__(256) void k_norm1(const float* __restrict__ scale,
                        const float* __restrict__ shift,
                        const float* __restrict__ dn_out,
                        const float* __restrict__ new0, unsigned short* __restrict__ h1b)
{
    int idx = blockIdx.x * 256 + threadIdx.x;   // one per 4 elements
    int r = idx >> 4, q = idx & 15;
    float dn = dn_out[r];
    float4 v = *(const float4*)(new0 + (size_t)r * 64 + q * 4);
    float4 sc = *(const float4*)(scale + q * 4);
    float4 sh = *(const float4*)(shift + q * 4);
    unsigned short h0 = f2b((sc.x * v.x + sh.x) * dn);
    unsigned short h1 = f2b((sc.y * v.y + sh.y) * dn);
    unsigned short h2 = f2b((sc.z * v.z + sh.z) * dn);
    unsigned short h3 = f2b((sc.w * v.w + sh.w) * dn);
    unsigned p0 = (unsigned)h0 | ((unsigned)h1 << 16);
    unsigned p1 = (unsigned)h2 | ((unsigned)h3 << 16);
    *(uint2*)(h1b + (size_t)r * 64 + q * 4) = make_uint2(p0, p1);
}

// ---------------- layer1 MFMA GEMM (column-split waves, grid = NTILE, fused BN stats) ----------------
// out = gelu(aggb@W1+b1) + gelu((scale0*new0+shift0)@Wr1+br1); aggb is bf16.
// wave w owns output cols w*16..w*16+15 (both W and R paths), all 64 rows.
__global__ __launch_bounds__(256) void k_gemm1(
    const unsigned short* __restrict__ aggb, const float* __restrict__ new0,
    const unsigned short* __restrict__ Wt1,
    const float* __restrict__ b1_, const float* __restrict__ br1,
    const float* __restrict__ scale0, const float* __restrict__ shift0,
    float* __restrict__ out_new,
    float* __restrict__ psum1, float* __restrict__ psumsq1)
{
    __shared__ unsigned short xa[64][72];   // stride 144B = 9 x 16B
    __shared__ unsigned short xb[64][72];
    __shared__ float cs[64], cs2[64];
    int t = threadIdx.x;
    int lane = t & 63;
    int w = t >> 6;
    int g = lane >> 4, r16 = lane & 15;
    int rr = t >> 2, q4 = t & 3;

    bf16x8 bW[2], bR[2];
    {
        int n = w * 16 + r16;
        for (int ks = 0; ks < 2; ++ks) {
            bW[ks] = *(const bf16x8*)(Wt1 + n * 64 + ks * 32 + g * 8);
            bR[ks] = *(const bf16x8*)(Wt1 + (64 + n) * 64 + ks * 32 + g * 8);
        }
    }
    float bias1 = b1_[w * 16 + r16];
    float biasr = br1[w * 16 + r16];
    float4 sc_[4], sh_[4];
    for (int i = 0; i < 4; ++i) {
        sc_[i] = *(const float4*)(scale0 + q4 * 16 + i * 4);
        sh_[i] = *(const float4*)(shift0 + q4 * 16 + i * 4);
    }
    float s_ = 0.f, s2_ = 0.f;

    if (t < 64) { cs[t] = 0.f; cs2[t] = 0.f; }

    for (int tile = blockIdx.x; tile < NTILE; tile += gridDim.x) {
        int row0 = tile * 64;
        {
            int R = row0 + rr;
            bool ok = (R < N_NODES);
            const unsigned short* pa = aggb + (size_t)R * 64 + q4 * 16;
            const float* pb = new0 + (size_t)R * 64 + q4 * 16;
            for (int i = 0; i < 4; ++i) {
                uint2 va = ok ? *(const uint2*)(pa + i * 4) : make_uint2(0u, 0u);
                float4 vb = ok ? *(const float4*)(pb + i * 4) : make_float4(0.f, 0.f, 0.f, 0.f);
                vb.x = sc_[i].x * vb.x + sh_[i].x;
                vb.y = sc_[i].y * vb.y + sh_[i].y;
                vb.z = sc_[i].z * vb.z + sh_[i].z;
                vb.w = sc_[i].w * vb.w + sh_[i].w;
                unsigned pb0 = (unsigned)f2b(vb.x) | ((unsigned)f2b(vb.y) << 16);
                unsigned pb1 = (unsigned)f2b(vb.z) | ((unsigned)f2b(vb.w) << 16);
                *(uint2*)(&xa[rr][q4 * 16 + i * 4]) = va;
                *(uint2*)(&xb[rr][q4 * 16 + i * 4]) = make_uint2(pb0, pb1);
            }
        }
        __syncthreads();

        int c = w * 16 + r16;
        for (int rg16 = 0; rg16 < 4; ++rg16) {
            int arow = rg16 * 16 + r16;
            bf16x8 aA[2], aB[2];
            for (int ks = 0; ks < 2; ++ks) {
                aA[ks] = *(const bf16x8*)(&xa[arow][ks * 32 + g * 8]);
                aB[ks] = *(const bf16x8*)(&xb[arow][ks * 32 + g * 8]);
            }
            f32x4 accW = (f32x4){0.f, 0.f, 0.f, 0.f};
            f32x4 accR = (f32x4){0.f, 0.f, 0.f, 0.f};
            for (int ks = 0; ks < 2; ++ks) {
                accW = __builtin_amdgcn_mfma_f32_16x16x32_bf16(aA[ks], bW[ks], accW, 0, 0, 0);
                accR = __builtin_amdgcn_mfma_f32_16x16x32_bf16(aB[ks], bR[ks], accR, 0, 0, 0);
            }
            int Rbase = row0 + rg16 * 16 + g * 4;
            for (int rg = 0; rg < 4; ++rg) {
                int R = Rbase + rg;
                if (R < N_NODES) {
                    float v = gelu_exact(accW[rg] + bias1) + gelu_exact(accR[rg] + biasr);
                    out_new[(size_t)R * 64 + c] = v;
                    s_ += v;
                    s2_ += v * v;
                }
            }
        }
        __syncthreads();
    }

    // fused BN-stats partial reduce (cs was zeroed before first barrier)
    atomicAdd(&cs[w * 16 + r16], s_);
    atomicAdd(&cs2[w * 16 + r16], s2_);
    __syncthreads();
    if (t < 64) {
        psum1[blockIdx.x * 64 + t] = cs[t];
        psumsq1[blockIdx.x * 64 + t] = cs2[t];
    }
}

// ---------------- head ----------------
__global__ void k_final(const int* __restrict__ offsets,
                        const float* __restrict__ h2,
                        const float* __restrict__ scale, const float* __restrict__ shift,
                        const float* __restrict__ Wl, const float* __restrict__ bl,
                        float* __restrict__ out)
{
    __shared__ float xv[64];
    int g = blockIdx.x;
    int t = threadIdx.x;
    int row = offsets[g];
    if (t < 64) xv[t] = h2[(size_t)row * 64 + t] * scale[t] + shift[t];
    __syncthreads();
    if (t < N_CLS) {
        float s = bl[t];
        for (int k = 0; k < 64; ++k) s += xv[k] * Wl[k * N_CLS + t];
        out[g * N_CLS + t] = s;
    }
}

extern "C" void kernel_launch(void* const* d_in, const int* in_sizes, int n_in,
                              void* d_out, int out_size, void* d_ws, size_t ws_size,
                              hipStream_t stream)
{
    const float* feats = (const float*)d_in[0];
    const int* src     = (const int*)d_in[1];
    const int* dst     = (const int*)d_in[2];
    const int* offsets = (const int*)d_in[3];
    const float* W0  = (const float*)d_in[4];
    const float* b0  = (const float*)d_in[5];
    const float* Wr0 = (const float*)d_in[6];
    const float* br0 = (const float*)d_in[7];
    const float* g0  = (const float*)d_in[8];
    const float* be0 = (const float*)d_in[9];
    const float* W1  = (const float*)d_in[10];
    const float* b1  = (const float*)d_in[11];
    const float* Wr1 = (const float*)d_in[12];
    const float* br1 = (const float*)d_in[13];
    const float* g1  = (const float*)d_in[14];
    const float* be1 = (const float*)d_in[15];
    const float* Wl  = (const float*)d_in[16];
    const float* bl  = (const float*)d_in[17];
    float* out = (float*)d_out;

    char* ws = (char*)d_ws;
    size_t off = 0;
    auto alloc = [&](size_t bytes) -> void* {
        off = (off + 255) & ~(size_t)255;
        void* p = ws + off;
        off += bytes;
        return p;
    };

    const size_t NB = (size_t)N_NODES * HID * sizeof(float);  // 25.6MB
    unsigned short* Hb = (unsigned short*)alloc(NB / 2);  // h0b / h1b (bf16)
    float* B = (float*)alloc(NB);                         // res0 -> new0
    float* C = (float*)alloc(NB);                         // hist partials (early) / new1
    unsigned* P = (unsigned*)C;                           // 16.8MB alias, dead before k_gemm1
    unsigned short* Ab = (unsigned short*)alloc(NB / 2);  // bf16 aggs (layer1): N_NODES*64*2B = 12.8MB
    unsigned short* Wt0 = (unsigned short*)alloc(128 * 128 * sizeof(unsigned short));
    unsigned short* Wt1 = (unsigned short*)alloc(128 * 64 * sizeof(unsigned short));
    int* cnt_in = (int*)alloc((size_t)N_NODES * sizeof(int));
    float* dn_out = (float*)alloc(N_NODES * sizeof(float));
    float* dn_in  = (float*)alloc(N_NODES * sizeof(float));
    int* bsum = (int*)alloc(SCAN_BLK * sizeof(int));
    int* bpre = (int*)alloc(SCAN_BLK * sizeof(int));
    int* row_start = (int*)alloc((SCAN_BLK * 256 + 1) * sizeof(int));
    int* csr_src   = (int*)alloc((size_t)N_EDGES * sizeof(int));
    double* psum   = (double*)alloc((size_t)SB * 64 * sizeof(double));
    double* psumsq = (double*)alloc((size_t)SB * 64 * sizeof(double));
    float* psum1   = (float*)alloc((size_t)NTILE * 64 * sizeof(float));
    float* psumsq1 = (float*)alloc((size_t)NTILE * 64 * sizeof(float));
    double* dsum   = (double*)alloc(64 * sizeof(double));
    double* dsumsq = (double*)alloc(64 * sizeof(double));
    float* scale0 = (float*)alloc(64 * sizeof(float));
    float* shift0 = (float*)alloc(64 * sizeof(float));
    float* scale1 = (float*)alloc(64 * sizeof(float));
    float* shift1 = (float*)alloc(64 * sizeof(float));
    (void)ws_size; (void)n_in; (void)in_sizes; (void)out_size;

    // weight prep + degree histograms + CSR (reused by both layers)
    k_prep_w<<<64, 256, 0, stream>>>(W0, Wr0, W1, Wr1, Wt0, Wt1);
    k_hist<<<2 * HNR * HNC, 256, 0, stream>>>(src, dst, P);
    k_hist_reduce<<<HNR * HWORDS / 256, 256, 0, stream>>>(P, cnt_in, dn_in, dn_out);
    k_scan_reduce<<<SCAN_BLK, 256, 0, stream>>>(cnt_in, bsum);
    k_scan_bsum<<<1, 512, 0, stream>>>(bsum, bpre);
    k_scan_write<<<SCAN_BLK, 256, 0, stream>>>(cnt_in, bpre, row_start);
    k_fill2<<<FNR * HNC, 256, 0, stream>>>(src, dst, row_start, P, csr_src);

    // layer 0
    k_gemm0<<<NTILE, 256, 0, stream>>>(feats, Wt0, br0, dn_out, Hb, B);
    k_agg<0><<<N_NODES / 4, 256, 0, stream>>>(row_start, csr_src, Hb, dn_in, b0, B, nullptr);
    k_stats_partial<<<SB, 256, 0, stream>>>(B, psum, psumsq);
    k_colred<double, SB><<<64, 256, 0, stream>>>(psum, psumsq, dsum, dsumsq);
    k_bn_final<<<1, 64, 0, stream>>>(dsum, dsumsq, g0, be0, scale0, shift0);
    k_norm1<<<(N_NODES * HID / 4) / 256, 256, 0, stream>>>(scale0, shift0, dn_out, B, Hb);

    // layer 1
    k_agg<1><<<N_NODES / 4, 256, 0, stream>>>(row_start, csr_src, Hb, dn_in, nullptr, nullptr, Ab);
    k_gemm1<<<NTILE, 256, 0, stream>>>(Ab, B, Wt1, b1, br1, scale0, shift0, C, psum1, psumsq1);
    k_colred<float, NTILE><<<64, 256, 0, stream>>>(psum1, psumsq1, dsum, dsumsq);
    k_bn_final<<<1, 64, 0, stream>>>(dsum, dsumsq, g1, be1, scale1, shift1);

    // head
    k_final<<<N_GRAPHS, 64, 0, stream>>>(offsets, C, scale1, shift1, Wl, bl, out);
}